// Round 9
// baseline (480.246 us; speedup 1.0000x reference)
//
#include <hip/hip_runtime.h>

typedef unsigned int u32;
typedef _Float16 f16;
typedef __attribute__((ext_vector_type(8))) _Float16 f16x8;
typedef __attribute__((ext_vector_type(4))) _Float16 f16x4;
typedef __attribute__((ext_vector_type(4))) float f32x4;

#define NNODES 100000
#define NEDGES 600000
#define CC 16
#define HH 48
#define NL 5
#define ECNB 9375                  // 9375 * 64 = 600000 exact (1 tile of 64 edges per block)
#define NBS 391                    // ceil(100000/256) scan blocks

// ---- ws layout (float units), total 4,000,064 floats = 16.0 MB ----
// TIMELINE-aliased regions:
//   OSCAN aliases OAGG: bsum/boff live only during scan_p1..p3; agg's memset
//   and first use are strictly after scatter_perm in stream order.
//   OXH0 aliases OX1+OX2: xh0 (split-f16 node feats, 100K x 32 f16 = 1.6M fl)
//   lives [conv_x0 .. nc1]; xh1 written by finh1 (after nc1), xh2 by finh2.
#define OX1   0                    // xh1 f16 (after finh1)
#define OXH0  0                    // xh0 f16 [conv_x0..nc1], spans OX1+OX2
#define OX2   800000               // xh2 f16 (after finh2)
#define OAGG  1600000              // agg fp32 [1.6M, 3.2M)
#define OSCAN 1600000              // scan scratch, dead before agg memset
#define OROW  3200000
#define ODEG  3300032              // deg during CSR build; then gf + gfn (f16)
#define OGF   3300032
#define OPERM 3400032
#define OSL   4000032
#define WS_NEED_FLOATS 4000064

// =================== CSR build ===================
__global__ __launch_bounds__(256) void count_deg(const int* __restrict__ ei, int* __restrict__ deg){
  int e = blockIdx.x * 256 + threadIdx.x;
  if (e >= NEDGES) return;
  atomicAdd(&deg[ei[NEDGES + e]], 1);
}

// ---- multi-block exclusive scan of deg -> rowptr ----
__global__ __launch_bounds__(256) void scan_p1(const int* __restrict__ deg, int* __restrict__ bsum){
  __shared__ int red[256];
  int b = blockIdx.x, t = threadIdx.x;
  int i = b * 256 + t;
  red[t] = (i < NNODES) ? deg[i] : 0;
  __syncthreads();
  for (int off = 128; off; off >>= 1){
    if (t < off) red[t] += red[t + off];
    __syncthreads();
  }
  if (t == 0) bsum[b] = red[0];
}

__global__ __launch_bounds__(512) void scan_p2(const int* __restrict__ bsum,
    int* __restrict__ boff, int* __restrict__ rowptr){
  __shared__ int s[512];
  int t = threadIdx.x;
  s[t] = (t < NBS) ? bsum[t] : 0;
  __syncthreads();
  for (int off = 1; off < 512; off <<= 1){
    int v = (t >= off) ? s[t - off] : 0;
    __syncthreads();
    s[t] += v;
    __syncthreads();
  }
  if (t < NBS) boff[t] = (t == 0) ? 0 : s[t - 1];
  if (t == 0) rowptr[NNODES] = s[NBS - 1];
}

__global__ __launch_bounds__(256) void scan_p3(const int* __restrict__ deg,
    const int* __restrict__ boff, int* __restrict__ rowptr){
  __shared__ int s[256];
  int b = blockIdx.x, t = threadIdx.x;
  int i = b * 256 + t;
  int d = (i < NNODES) ? deg[i] : 0;
  s[t] = d;
  __syncthreads();
  for (int off = 1; off < 256; off <<= 1){
    int v = (t >= off) ? s[t - off] : 0;
    __syncthreads();
    s[t] += v;
    __syncthreads();
  }
  if (i < NNODES) rowptr[i] = boff[b] + s[t] - d;
}

__global__ __launch_bounds__(256) void scatter_perm(const int* __restrict__ ei,
    const int* __restrict__ rowptr, int* __restrict__ deg2, int* __restrict__ perm){
  int e = blockIdx.x * 256 + threadIdx.x;
  if (e >= NEDGES) return;
  int d = ei[NEDGES + e];
  int pos = rowptr[d] + atomicAdd(&deg2[d], 1);
  perm[pos] = e;
}

// ======== split-f16 node features, computed ONCE (was per-edge in nc1) ========
__global__ __launch_bounds__(256) void conv_x0(const float* __restrict__ nf, f16* __restrict__ xh0){
  int n = blockIdx.x * 256 + threadIdx.x;
  if (n >= NNODES) return;
  const float4* p = (const float4*)(nf + (long)n * 16);
  float4 v0 = p[0], v1 = p[1], v2 = p[2], v3 = p[3];
  float x[16] = {v0.x,v0.y,v0.z,v0.w, v1.x,v1.y,v1.z,v1.w,
                 v2.x,v2.y,v2.z,v2.w, v3.x,v3.y,v3.z,v3.w};
  f16x8 hiA, hiB, loA, loB;
  #pragma unroll
  for (int k = 0; k < 8; k++){
    f16 h = (f16)x[k];     hiA[k] = h; loA[k] = (f16)(x[k] - (float)h);
    f16 h2 = (f16)x[8+k];  hiB[k] = h2; loB[k] = (f16)(x[8+k] - (float)h2);
  }
  f16* o = &xh0[(long)n * 32];
  *(f16x8*)&o[0]  = hiA;
  *(f16x8*)&o[8]  = hiB;
  *(f16x8*)&o[16] = loA;
  *(f16x8*)&o[24] = loB;
}

// =================== final loss write (ec writes out[] directly) ===================
__global__ void fin_loss(const float* __restrict__ slacc, float* __restrict__ out){
  out[NEDGES] = slacc[0] * (1.0f / 57600000.0f);  // loss = S/(2*48*E)
}

// ============ EC W-fragment precompute (r13-proven) ============
__global__ __launch_bounds__(256) void prep_wfrag(
    const float* __restrict__ e1w0, const float* __restrict__ e1wh, const float* __restrict__ e1wc,
    const float* __restrict__ e2w0, const float* __restrict__ e2wh, f16* __restrict__ gf)
{
  int idx = blockIdx.x * 256 + threadIdx.x;
  if (idx >= 39936) return;
  int j = idx & 7, lane = (idx >> 3) & 63, f = idx >> 9;
  int wt = f % 3, ksl = f / 3;
  int ks = ksl & 1, lay = ksl >> 1;
  int k = ks * 32 + ((lane >> 4) << 3) + j;
  int m = wt * 16 + (lane & 15);
  const float* w; int Kl;
  if (lay == 0){ w = e1w0; Kl = 32; }
  else if (lay <= 5){ w = e1wh + (lay - 1) * 2304; Kl = 48; }
  else if (lay == 6){ w = e1wc; Kl = 48; }
  else if (lay == 7){ w = e2w0; Kl = 32; }
  else { w = e2wh + (lay - 8) * 2304; Kl = 48; }
  gf[idx] = (k < Kl) ? (f16)w[k * 48 + m] : (f16)0.f;
}

// ============ NC W-fragments, SPLIT precision (r20-proven) ============
__global__ __launch_bounds__(256) void prep_wfrag_nc(
    const float* __restrict__ n1w0, const float* __restrict__ n1wh,
    const float* __restrict__ n2w0, const float* __restrict__ n2wh,
    f16* __restrict__ gfn)
{
  int idx = blockIdx.x * 256 + threadIdx.x;
  if (idx >= 24 * 512) return;
  int j = idx & 7, lane = (idx >> 3) & 63, f = idx >> 9;
  int conv = f / 12, slot = f % 12;
  int kq = ((lane >> 4) << 3) + j;
  int m = lane & 15;
  const float* w0 = conv ? n2w0 : n1w0;
  const float* wh = conv ? n2wh : n1wh;
  float val;
  bool wantLo;
  if (slot <= 1){
    val = w0[kq * 16 + m];
    wantLo = (slot == 1);
  } else {
    int l = (slot - 2) >> 1;
    bool isB = (slot - 2) & 1;
    const float* wl = wh + l * 256;
    if (!isB){ val = wl[(kq & 15) * 16 + m]; wantLo = false; }
    else if (kq < 16){ val = wl[kq * 16 + m]; wantLo = true; }
    else { gfn[idx] = (f16)0.f; return; }
  }
  f16 hi = (f16)val;
  gfn[idx] = wantLo ? (f16)(val - (float)hi) : hi;
}

// ============================================================================
// NodeConv via MFMA, SPLIT-f16 (r20-proven math), BARRIER-FREE.
// r9 rework:
//  - Per-thread OWN-EDGE metadata (3 random gathers: ang, dst, src) + 8 __shfl
//    to distribute per-et angv/dkv across the wave (was 9 random gathers).
//    Identity: old pev[q] for the staging row == perm[base+t] exactly.
//  - WIDE path (NC1) reads precomputed split-f16 xh0 (hi16|lo16 per node):
//    8 contiguous f16x8 loads placed in the SAME chunk layout the fp32 path
//    produced (c0,c1=d-hi; c2,c3=s-hi; c4,c5=d-lo; c6,c7=s-lo) -> bit-identical.
// __launch_bounds__(256,4): spill-free regime (r4 calibration).
// ============================================================================
template<bool WIDE>
__global__ __launch_bounds__(256, 4) void nc_mfma(
    const f16* __restrict__ xin, const int* __restrict__ ei,
    const float* __restrict__ ang, const int* __restrict__ perm,
    const f16* __restrict__ gfn,
    const float* __restrict__ w0f,
    const float* __restrict__ b0, const float* __restrict__ bh,
    float* __restrict__ agg)
{
  constexpr int RW  = WIDE ? 64 : 32;   // row width in f16
  constexpr int RSH = WIDE ? 6  : 5;    // row shift
  constexpr int RSM = WIDE ? 7  : 3;    // chunk swizzle mask
  __shared__ __align__(16) f16 Hn[256 * RW];

  const int t = threadIdx.x, lane = t & 63, wv = t >> 6;
  const int q = lane >> 4, n15 = lane & 15;
  const int base = blockIdx.x * 256;

  // own-edge metadata (1 contiguous + 3 random gathers)
  int gi = base + t;
  int gic = gi < NEDGES ? gi : NEDGES - 1;
  int pe = perm[gic];
  float aOwn = ang[pe];
  int dOwn = ei[NEDGES + pe];
  int sOwn = ei[pe];

  // distribute per-et metadata via wave shuffles
  float angv[4]; int dkv[4];
  #pragma unroll
  for (int et = 0; et < 4; et++){
    int sl = et * 16 + n15;
    angv[et] = __shfl(aOwn, sl);
    dkv[et]  = __shfl(dOwn, sl);
  }

  { // stage own row t (wave-private)
    int rs = t & RSM;
    f16* hp = &Hn[t << RSH];
    if (WIDE){
      const f16* pd = &xin[(long)dOwn * 32];
      const f16* ps = &xin[(long)sOwn * 32];
      f16x8 dh0 = *(const f16x8*)&pd[0],  dh1 = *(const f16x8*)&pd[8];
      f16x8 dl0 = *(const f16x8*)&pd[16], dl1 = *(const f16x8*)&pd[24];
      f16x8 sh0 = *(const f16x8*)&ps[0],  sh1 = *(const f16x8*)&ps[8];
      f16x8 sl0 = *(const f16x8*)&ps[16], sl1 = *(const f16x8*)&ps[24];
      *(f16x8*)&hp[(0 ^ rs) << 3] = dh0;
      *(f16x8*)&hp[(1 ^ rs) << 3] = dh1;
      *(f16x8*)&hp[(2 ^ rs) << 3] = sh0;
      *(f16x8*)&hp[(3 ^ rs) << 3] = sh1;
      *(f16x8*)&hp[(4 ^ rs) << 3] = dl0;
      *(f16x8*)&hp[(5 ^ rs) << 3] = dl1;
      *(f16x8*)&hp[(6 ^ rs) << 3] = sl0;
      *(f16x8*)&hp[(7 ^ rs) << 3] = sl1;
    } else {
      f16x8 r0 = *(const f16x8*)&xin[(long)dOwn * 16];
      f16x8 r1 = *(const f16x8*)&xin[(long)dOwn * 16 + 8];
      f16x8 r2 = *(const f16x8*)&xin[(long)sOwn * 16];
      f16x8 r3 = *(const f16x8*)&xin[(long)sOwn * 16 + 8];
      *(f16x8*)&hp[(0 ^ rs) << 3] = r0;
      *(f16x8*)&hp[(1 ^ rs) << 3] = r1;
      *(f16x8*)&hp[(2 ^ rs) << 3] = r2;
      *(f16x8*)&hp[(3 ^ rs) << 3] = r3;
    }
  }
  // no __syncthreads(): all LDS reads below are of this wave's own rows

  float4 wang = *(const float4*)&w0f[32 * 16 + 4 * q];

  f32x4 C[4];
  for (int lay = 0; lay < 6; lay++){
    const float* bp = (lay == 0) ? b0 : &bh[(lay - 1) * 16];
    float4 b4 = *(const float4*)&bp[4 * q];
    #pragma unroll
    for (int et = 0; et < 4; et++){
      C[et] = (f32x4){b4.x, b4.y, b4.z, b4.w};
      if (lay == 0){
        float a = angv[et];
        C[et][0] += a * wang.x; C[et][1] += a * wang.y;
        C[et][2] += a * wang.z; C[et][3] += a * wang.w;
      }
    }
    const int nst = (lay == 0) ? (WIDE ? 3 : 2) : 2;
    #pragma unroll 3
    for (int st = 0; st < nst; st++){
      int fr, cb;
      if (lay == 0){
        if (WIDE){ fr = (st == 2) ? 1 : 0; cb = (st == 1) ? 4 : 0; }
        else     { fr = st; cb = 0; }
      }
      else { fr = 2 + 2 * (lay - 1) + st; cb = 0; }
      f16x8 Af = *(const f16x8*)&gfn[(fr << 9) + (lane << 3)];
      int c = cb + q;
      #pragma unroll
      for (int et = 0; et < 4; et++){
        int r = wv * 64 + et * 16 + n15;
        f16x8 Bf = *(const f16x8*)&Hn[(r << RSH) + ((c ^ (r & RSM)) << 3)];
        C[et] = __builtin_amdgcn_mfma_f32_16x16x32_f16(Af, Bf, C[et], 0, 0, 0);
      }
    }
    if (lay < 5){
      #pragma unroll
      for (int et = 0; et < 4; et++){
        int r = wv * 64 + et * 16 + n15;
        f16x4 hi4, lo4;
        #pragma unroll
        for (int reg = 0; reg < 4; reg++){
          float v = fmaxf(C[et][reg], 0.f);
          f16 h = (f16)v;
          hi4[reg] = h;
          lo4[reg] = (f16)(v - (float)h);
        }
        int ch = 4 * q;
        *(f16x4*)&Hn[(r << RSH) + ((((ch >> 3) ^ (r & RSM)) << 3) | (ch & 7))] = hi4;
        int cl = 16 + 4 * q;
        *(f16x4*)&Hn[(r << RSH) + ((((cl >> 3) ^ (r & RSM)) << 3) | (cl & 7))] = lo4;
      }
    } else {
      #pragma unroll
      for (int et = 0; et < 4; et++){
        int li = wv * 64 + et * 16 + n15;
        bool valid = (base + li) < NEDGES;
        int dk = valid ? dkv[et] : -1;
        bool sm[4];
        int o = 1;
        #pragma unroll
        for (int k2 = 0; k2 < 4; k2++, o <<= 1){
          int dn = __shfl_down(dk, o);
          sm[k2] = (n15 + o < 16) && (dn == dk);
        }
        int dprev = __shfl_up(dk, 1);
        bool head = valid && ((n15 == 0) || (dprev != dk));
        #pragma unroll
        for (int reg = 0; reg < 4; reg++){
          float v = valid ? fmaxf(C[et][reg], 0.f) : 0.f;
          o = 1;
          #pragma unroll
          for (int k2 = 0; k2 < 4; k2++, o <<= 1){
            float vn = __shfl_down(v, o);
            if (sm[k2]) v += vn;
          }
          if (head) atomicAdd(&agg[(long)dk * 16 + 4 * q + reg], v);
        }
      }
    }
  }
}

// ---- finalize: xh[n] = f16( agg[n] / max(deg,1) ); re-zeroes agg in place ----
__global__ __launch_bounds__(256) void node_finh(
    float* __restrict__ agg, const int* __restrict__ rowptr, f16* __restrict__ xh)
{
  int n = blockIdx.x * 256 + threadIdx.x;
  if (n >= NNODES) return;
  float inv = 1.f / fmaxf((float)(rowptr[n+1] - rowptr[n]), 1.f);
  float4* ap = (float4*)&agg[(long)n * 16];
  float4 z = {0.f, 0.f, 0.f, 0.f};
  f16x8 o0, o1;
  #pragma unroll
  for (int k = 0; k < 2; k++){
    float4 v = ap[k];
    o0[4*k] = (f16)(v.x*inv); o0[4*k+1] = (f16)(v.y*inv);
    o0[4*k+2] = (f16)(v.z*inv); o0[4*k+3] = (f16)(v.w*inv);
    ap[k] = z;
  }
  #pragma unroll
  for (int k = 0; k < 2; k++){
    float4 v = ap[2+k];
    o1[4*k] = (f16)(v.x*inv); o1[4*k+1] = (f16)(v.y*inv);
    o1[4*k+2] = (f16)(v.z*inv); o1[4*k+3] = (f16)(v.w*inv);
    ap[2+k] = z;
  }
  *(f16x8*)&xh[(long)n * 16]     = o0;
  *(f16x8*)&xh[(long)n * 16 + 8] = o1;
}

// ============================================================================
// Fused EdgeConv1+EdgeConv2, BARRIER-FREE, 1 tile (64 edges) per block.
// NATURAL EDGE ORDER: act[e], ei[e], out[e] contiguous; only xh gathers random.
// ef folded into outAcc at conv1 time (linear functional).
// __launch_bounds__(256,5): spill-free (r8 verified: VGPR 48, WRITE 2.6MB).
// ============================================================================
__global__ __launch_bounds__(256, 5) void ec_mfma(
    const f16* __restrict__ xh1, const f16* __restrict__ xh2,
    const int* __restrict__ ei,
    const float* __restrict__ act, const f16* __restrict__ gf,
    const float* __restrict__ e1wc, const float* __restrict__ e1b0,
    const float* __restrict__ e1bh, const float* __restrict__ e1bc,
    const float* __restrict__ e2b0, const float* __restrict__ e2bh,
    const float* __restrict__ e2wc, const float* __restrict__ e2bc,
    float* __restrict__ outG, float* __restrict__ slacc)
{
  __shared__ __align__(16) f16 Hb[128 * 64];
  __shared__ float sred[4];

  const int t = threadIdx.x;
  const int lane = t & 63;
  const int wv = t >> 6;
  const int q = lane >> 4, n15 = lane & 15;
  const int eidx = (lane >> 1) & 15;      // edge within wave (staging)
  const int fh   = lane >> 5;             // 0: f1 rows, 1: f2 rows
  const int sub  = lane & 1;              // chunk pair selector
  const int myrow = fh * 64 + wv * 16 + eidx;
  const int gebase = blockIdx.x * 64;

  // staging node (f1=[x_d|x_s], f2=[x_s|x_d]); natural edge order, contiguous ei
  const int node = ei[((fh ^ sub) ? 0 : NEDGES) + gebase + wv * 16 + eidx];
  // this lane's output edge (contiguous act read / out write)
  const int e2 = gebase + wv * 16 + n15;
  const float aL = act[e2];

  const int rs = myrow & 7;
  auto store_lds = [&](const f16* __restrict__ xh){
    f16x8 pa0 = *(const f16x8*)&xh[(long)node * 16];
    f16x8 pa1 = *(const f16x8*)&xh[(long)node * 16 + 8];
    f16* hp = &Hb[myrow << 6];
    *(f16x8*)&hp[((2*sub)     ^ rs) << 3] = pa0;
    *(f16x8*)&hp[((2*sub + 1) ^ rs) << 3] = pa1;
    if (sub){
      f16x8 z = {};
      *(f16x8*)&hp[(6 ^ rs) << 3] = z;
      *(f16x8*)&hp[(7 ^ rs) << 3] = z;
    }
  };

  float side = 0.f;
  float outAcc = 0.f;   // accumulates ef·wb at mode 2, then fe·wa at mode 3

  auto layer = [&](int lay, const float* bias, int nks, int mode){
    const int nEt = (mode == 2) ? 1 : 2;
    f32x4 C[3][2];
    #pragma unroll
    for (int wt = 0; wt < 3; wt++){
      float4 b4 = *(const float4*)&bias[wt*16 + 4*q];
      C[wt][0] = (f32x4){b4.x, b4.y, b4.z, b4.w};
      C[wt][1] = C[wt][0];
    }
    for (int ks = 0; ks < nks; ks++){
      int c = ks*4 + q;
      f16x8 Af[3];
      #pragma unroll
      for (int wt = 0; wt < 3; wt++)
        Af[wt] = *(const f16x8*)&gf[((((lay*2 + ks)*3) + wt) << 9) + (lane << 3)];
      for (int et = 0; et < nEt; et++){
        int r = (et << 6) + wv*16 + n15;
        f16x8 Bf = *(const f16x8*)&Hb[(r << 6) + ((c ^ (r & 7)) << 3)];
        #pragma unroll
        for (int wt = 0; wt < 3; wt++)
          C[wt][et] = __builtin_amdgcn_mfma_f32_16x16x32_f16(Af[wt], Bf, C[wt][et], 0, 0, 0);
      }
    }
    if (mode == 0){
      #pragma unroll
      for (int et = 0; et < 2; et++){
        int r = (et << 6) + wv*16 + n15;
        #pragma unroll
        for (int wt = 0; wt < 3; wt++){
          f16x4 pk;
          #pragma unroll
          for (int reg = 0; reg < 4; reg++) pk[reg] = (f16)fmaxf(C[wt][et][reg], 0.f);
          int col = wt*16 + 4*q;
          *(f16x4*)&Hb[(r << 6) + ((((col >> 3) ^ (r & 7)) << 3) | (col & 7))] = pk;
        }
      }
    } else if (mode == 1){
      int r = wv*16 + n15;
      #pragma unroll
      for (int wt = 0; wt < 3; wt++){
        f16x4 pk;
        #pragma unroll
        for (int reg = 0; reg < 4; reg++){
          float v1 = fmaxf(C[wt][0][reg], 0.f);
          float v2 = fmaxf(C[wt][1][reg], 0.f);
          float dd = v1 - v2; side += dd * dd;
          pk[reg] = (f16)(0.5f * (v1 + v2));
        }
        int col = wt*16 + 4*q;
        *(f16x4*)&Hb[(r << 6) + ((((col >> 3) ^ (r & 7)) << 3) | (col & 7))] = pk;
      }
    } else if (mode == 2){
      // ef = C + aL*wr; consumed only as sum(ef * e2wc[48..96]) -> fold now
      #pragma unroll
      for (int wt = 0; wt < 3; wt++){
        float4 wr = *(const float4*)&e1wc[2304 + wt*16 + 4*q];
        float4 wb = *(const float4*)&e2wc[48 + wt*16 + 4*q];
        outAcc += (C[wt][0][0] + aL * wr.x) * wb.x
                + (C[wt][0][1] + aL * wr.y) * wb.y
                + (C[wt][0][2] + aL * wr.z) * wb.z
                + (C[wt][0][3] + aL * wr.w) * wb.w;
      }
    } else {
      #pragma unroll
      for (int wt = 0; wt < 3; wt++){
        float4 wa = *(const float4*)&e2wc[wt*16 + 4*q];
        float av[4] = {wa.x, wa.y, wa.z, wa.w};
        #pragma unroll
        for (int reg = 0; reg < 4; reg++){
          float v1 = fmaxf(C[wt][0][reg], 0.f);
          float v2 = fmaxf(C[wt][1][reg], 0.f);
          float dd = v1 - v2; side += dd * dd;
          float fe = 0.5f * (v1 + v2);
          outAcc += fe * av[reg];
        }
      }
    }
  };

  // stage conv1 input (wave-private, no barrier)
  store_lds(xh1);

  // ---- EdgeConv1 ----
  layer(0, e1b0,        1, 0);
  layer(1, e1bh + 0*48, 2, 0);
  layer(2, e1bh + 1*48, 2, 0);
  layer(3, e1bh + 2*48, 2, 0);
  layer(4, e1bh + 3*48, 2, 0);
  layer(5, e1bh + 4*48, 2, 1);
  layer(6, e1bc,        2, 2);   // ef·wb folded into outAcc

  // restage same buffer with conv2 input (wave-private, in-order DS; xh2 L2-hot)
  store_lds(xh2);

  // ---- EdgeConv2 ----
  layer(7,  e2b0,        1, 0);
  layer(8,  e2bh + 0*48, 2, 0);
  layer(9,  e2bh + 1*48, 2, 0);
  layer(10, e2bh + 2*48, 2, 0);
  layer(11, e2bh + 3*48, 2, 0);
  layer(12, e2bh + 4*48, 2, 3);  // fe·wa into outAcc

  {
    float v = outAcc;
    v += __shfl_xor(v, 16);
    v += __shfl_xor(v, 32);
    if (lane < 16) outG[e2] = v + e2bc[0];   // contiguous write
  }

  // side-loss: one atomic per block
  float sv = side;
  #pragma unroll
  for (int off = 32; off; off >>= 1) sv += __shfl_down(sv, off);
  if (lane == 0) sred[wv] = sv;
  __syncthreads();
  if (t == 0) atomicAdd(slacc, sred[0] + sred[1] + sred[2] + sred[3]);
}

// ================= launch ==================
extern "C" void kernel_launch(void* const* d_in, const int* in_sizes, int n_in,
                              void* d_out, int out_size, void* d_ws, size_t ws_size,
                              hipStream_t stream)
{
  if (n_in < 25) return;
  if (ws_size < (size_t)WS_NEED_FLOATS * sizeof(float)) return;

  const float* nf  = (const float*)d_in[0];
  const int*   ei  = (const int*)d_in[1];
  const float* ang = (const float*)d_in[2];
  const float* act = (const float*)d_in[4];
  const float* nc1_w0 = (const float*)d_in[5];
  const float* nc1_b0 = (const float*)d_in[6];
  const float* nc1_wh = (const float*)d_in[7];
  const float* nc1_bh = (const float*)d_in[8];
  const float* nc2_w0 = (const float*)d_in[9];
  const float* nc2_b0 = (const float*)d_in[10];
  const float* nc2_wh = (const float*)d_in[11];
  const float* nc2_bh = (const float*)d_in[12];
  const float* e1w0 = (const float*)d_in[13];
  const float* e1b0 = (const float*)d_in[14];
  const float* e1wh = (const float*)d_in[15];
  const float* e1bh = (const float*)d_in[16];
  const float* e1wc = (const float*)d_in[17];
  const float* e1bc = (const float*)d_in[18];
  const float* e2w0 = (const float*)d_in[19];
  const float* e2b0 = (const float*)d_in[20];
  const float* e2wh = (const float*)d_in[21];
  const float* e2bh = (const float*)d_in[22];
  const float* e2wc = (const float*)d_in[23];
  const float* e2bc = (const float*)d_in[24];

  float* ws  = (float*)d_ws;
  float* out = (float*)d_out;

  f16* xh1    = (f16*)(ws + OX1);
  f16* xh0    = (f16*)(ws + OXH0);
  f16* xh2    = (f16*)(ws + OX2);
  float* agg  = ws + OAGG;
  int* rowptr = (int*)(ws + OROW);
  int* deg    = (int*)(ws + ODEG);
  f16* gf     = (f16*)(ws + OGF);
  f16* gfn    = gf + 39936;
  int* bsum   = (int*)(ws + OSCAN);
  int* boff   = bsum + 512;
  int* perm   = (int*)(ws + OPERM);
  float* sl   = ws + OSL;

  const int eb  = (NEDGES + 255) / 256;
  const int nbN = (NNODES + 255) / 256;
  const int pfb = (39936 + 255) / 256;
  const int pnb = (12288 + 255) / 256;

  (void)hipMemsetAsync(deg, 0, (size_t)NNODES * sizeof(int), stream);
  (void)hipMemsetAsync(sl, 0, sizeof(float), stream);

  hipLaunchKernelGGL(count_deg, dim3(eb), dim3(256), 0, stream, ei, deg);
  hipLaunchKernelGGL(scan_p1, dim3(NBS), dim3(256), 0, stream, deg, bsum);
  hipLaunchKernelGGL(scan_p2, dim3(1), dim3(512), 0, stream, bsum, boff, rowptr);
  hipLaunchKernelGGL(scan_p3, dim3(NBS), dim3(256), 0, stream, deg, boff, rowptr);
  (void)hipMemsetAsync(deg, 0, (size_t)NNODES * sizeof(int), stream);
  hipLaunchKernelGGL(scatter_perm, dim3(eb), dim3(256), 0, stream, ei, rowptr, deg, perm);

  // split-f16 node features once (xh0 @ OX1+OX2, dead after nc1)
  hipLaunchKernelGGL(conv_x0, dim3(nbN), dim3(256), 0, stream, nf, xh0);

  hipLaunchKernelGGL(prep_wfrag, dim3(pfb), dim3(256), 0, stream,
      e1w0, e1wh, e1wc, e2w0, e2wh, gf);
  hipLaunchKernelGGL(prep_wfrag_nc, dim3(pnb), dim3(256), 0, stream,
      nc1_w0, nc1_wh, nc2_w0, nc2_wh, gfn);

  // NodeConv1: xh0 (split f16) -> agg -> xh1 (node_finh re-zeroes agg for NC2)
  // (agg memset also retires the scan scratch aliased at OSCAN)
  (void)hipMemsetAsync(agg, 0, (size_t)NNODES * 16 * sizeof(float), stream);
  hipLaunchKernelGGL((nc_mfma<true>), dim3(eb), dim3(256), 0, stream,
      xh0, ei, ang, perm, gfn, nc1_w0, nc1_b0, nc1_bh, agg);
  hipLaunchKernelGGL(node_finh, dim3(nbN), dim3(256), 0, stream, agg, rowptr, xh1);

  // NodeConv2: f16 xh1 -> agg -> xh2
  hipLaunchKernelGGL((nc_mfma<false>), dim3(eb), dim3(256), 0, stream,
      xh1, ei, ang, perm, gfn + 12 * 512, nc2_w0, nc2_b0, nc2_bh, agg);
  hipLaunchKernelGGL(node_finh, dim3(nbN), dim3(256), 0, stream, agg, rowptr, xh2);

  // fused EdgeConv1+2: natural edge order, all IO contiguous except xh gathers
  hipLaunchKernelGGL(ec_mfma, dim3(ECNB), dim3(256), 0, stream,
      xh1, xh2, ei, act, gf,
      e1wc, e1b0, e1bh, e1bc, e2b0, e2bh, e2wc, e2bc,
      out, sl);

  hipLaunchKernelGGL(fin_loss, dim3(1), dim3(1), 0, stream, sl, out);
}

// Round 11
// 462.996 us; speedup vs baseline: 1.0373x; 1.0373x over previous
//
#include <hip/hip_runtime.h>

typedef unsigned int u32;
typedef _Float16 f16;
typedef __attribute__((ext_vector_type(8))) _Float16 f16x8;
typedef __attribute__((ext_vector_type(4))) _Float16 f16x4;
typedef __attribute__((ext_vector_type(4))) float f32x4;

#define NNODES 100000
#define NEDGES 600000
#define CC 16
#define HH 48
#define NL 5
#define ECNB 9375                  // 9375 * 64 = 600000 exact (1 tile of 64 edges per block)
#define NBS 391                    // ceil(100000/256) scan blocks

// ---- ws layout (float units), total 4,000,064 floats = 16.0 MB ----
// TIMELINE-aliased regions:
//   OSCAN aliases OAGG: bsum/boff live only during scan_p1..p3; agg's memset
//   and first use are strictly after scatter_perm in stream order.
#define OX1   0                    // xh1 f16
#define OX2   800000               // xh2 f16
#define OAGG  1600000              // agg fp32 [1.6M, 3.2M)
#define OSCAN 1600000              // scan scratch, dead before agg memset
#define OROW  3200000
#define ODEG  3300032              // deg during CSR build; then gf + gfn (f16)
#define OGF   3300032
#define OPERM 3400032
#define OSL   4000032
#define WS_NEED_FLOATS 4000064

// =================== CSR build ===================
__global__ __launch_bounds__(256) void count_deg(const int* __restrict__ ei, int* __restrict__ deg){
  int e = blockIdx.x * 256 + threadIdx.x;
  if (e >= NEDGES) return;
  atomicAdd(&deg[ei[NEDGES + e]], 1);
}

// ---- multi-block exclusive scan of deg -> rowptr ----
__global__ __launch_bounds__(256) void scan_p1(const int* __restrict__ deg, int* __restrict__ bsum){
  __shared__ int red[256];
  int b = blockIdx.x, t = threadIdx.x;
  int i = b * 256 + t;
  red[t] = (i < NNODES) ? deg[i] : 0;
  __syncthreads();
  for (int off = 128; off; off >>= 1){
    if (t < off) red[t] += red[t + off];
    __syncthreads();
  }
  if (t == 0) bsum[b] = red[0];
}

__global__ __launch_bounds__(512) void scan_p2(const int* __restrict__ bsum,
    int* __restrict__ boff, int* __restrict__ rowptr){
  __shared__ int s[512];
  int t = threadIdx.x;
  s[t] = (t < NBS) ? bsum[t] : 0;
  __syncthreads();
  for (int off = 1; off < 512; off <<= 1){
    int v = (t >= off) ? s[t - off] : 0;
    __syncthreads();
    s[t] += v;
    __syncthreads();
  }
  if (t < NBS) boff[t] = (t == 0) ? 0 : s[t - 1];
  if (t == 0) rowptr[NNODES] = s[NBS - 1];
}

__global__ __launch_bounds__(256) void scan_p3(const int* __restrict__ deg,
    const int* __restrict__ boff, int* __restrict__ rowptr){
  __shared__ int s[256];
  int b = blockIdx.x, t = threadIdx.x;
  int i = b * 256 + t;
  int d = (i < NNODES) ? deg[i] : 0;
  s[t] = d;
  __syncthreads();
  for (int off = 1; off < 256; off <<= 1){
    int v = (t >= off) ? s[t - off] : 0;
    __syncthreads();
    s[t] += v;
    __syncthreads();
  }
  if (i < NNODES) rowptr[i] = boff[b] + s[t] - d;
}

__global__ __launch_bounds__(256) void scatter_perm(const int* __restrict__ ei,
    const int* __restrict__ rowptr, int* __restrict__ deg2, int* __restrict__ perm){
  int e = blockIdx.x * 256 + threadIdx.x;
  if (e >= NEDGES) return;
  int d = ei[NEDGES + e];
  int pos = rowptr[d] + atomicAdd(&deg2[d], 1);
  perm[pos] = e;
}

// =================== final loss write (ec writes out[] directly) ===================
__global__ void fin_loss(const float* __restrict__ slacc, float* __restrict__ out){
  out[NEDGES] = slacc[0] * (1.0f / 57600000.0f);  // loss = S/(2*48*E)
}

// ============ EC W-fragment precompute (r13-proven) ============
__global__ __launch_bounds__(256) void prep_wfrag(
    const float* __restrict__ e1w0, const float* __restrict__ e1wh, const float* __restrict__ e1wc,
    const float* __restrict__ e2w0, const float* __restrict__ e2wh, f16* __restrict__ gf)
{
  int idx = blockIdx.x * 256 + threadIdx.x;
  if (idx >= 39936) return;
  int j = idx & 7, lane = (idx >> 3) & 63, f = idx >> 9;
  int wt = f % 3, ksl = f / 3;
  int ks = ksl & 1, lay = ksl >> 1;
  int k = ks * 32 + ((lane >> 4) << 3) + j;
  int m = wt * 16 + (lane & 15);
  const float* w; int Kl;
  if (lay == 0){ w = e1w0; Kl = 32; }
  else if (lay <= 5){ w = e1wh + (lay - 1) * 2304; Kl = 48; }
  else if (lay == 6){ w = e1wc; Kl = 48; }
  else if (lay == 7){ w = e2w0; Kl = 32; }
  else { w = e2wh + (lay - 8) * 2304; Kl = 48; }
  gf[idx] = (k < Kl) ? (f16)w[k * 48 + m] : (f16)0.f;
}

// ============ NC W-fragments, SPLIT precision (r20-proven) ============
__global__ __launch_bounds__(256) void prep_wfrag_nc(
    const float* __restrict__ n1w0, const float* __restrict__ n1wh,
    const float* __restrict__ n2w0, const float* __restrict__ n2wh,
    f16* __restrict__ gfn)
{
  int idx = blockIdx.x * 256 + threadIdx.x;
  if (idx >= 24 * 512) return;
  int j = idx & 7, lane = (idx >> 3) & 63, f = idx >> 9;
  int conv = f / 12, slot = f % 12;
  int kq = ((lane >> 4) << 3) + j;
  int m = lane & 15;
  const float* w0 = conv ? n2w0 : n1w0;
  const float* wh = conv ? n2wh : n1wh;
  float val;
  bool wantLo;
  if (slot <= 1){
    val = w0[kq * 16 + m];
    wantLo = (slot == 1);
  } else {
    int l = (slot - 2) >> 1;
    bool isB = (slot - 2) & 1;
    const float* wl = wh + l * 256;
    if (!isB){ val = wl[(kq & 15) * 16 + m]; wantLo = false; }
    else if (kq < 16){ val = wl[kq * 16 + m]; wantLo = true; }
    else { gfn[idx] = (f16)0.f; return; }
  }
  f16 hi = (f16)val;
  gfn[idx] = wantLo ? (f16)(val - (float)hi) : hi;
}

// ============================================================================
// NodeConv via MFMA, SPLIT-f16 (r20-proven math), BARRIER-FREE.
// __launch_bounds__(256,4): spill-free regime (r4 calibration: bounds arg sets
// RA target ~256/N; targets below natural need ~55-70 spill to scratch).
// r9 experiment (shfl metadata + xh0 precompute) REVERTED: +15µs net (conv_x0
// overhead > gather savings; nc is not metadata-gather-bound).
// ============================================================================
template<bool FP32IN>
__global__ __launch_bounds__(256, 4) void nc_mfma(
    const void* __restrict__ xin, const int* __restrict__ ei,
    const float* __restrict__ ang, const int* __restrict__ perm,
    const f16* __restrict__ gfn,
    const float* __restrict__ w0f,
    const float* __restrict__ b0, const float* __restrict__ bh,
    float* __restrict__ agg)
{
  constexpr int RW  = FP32IN ? 64 : 32;   // row width in f16
  constexpr int RSH = FP32IN ? 6  : 5;    // row shift
  constexpr int RSM = FP32IN ? 7  : 3;    // chunk swizzle mask
  __shared__ __align__(16) f16 Hn[256 * RW];

  const int t = threadIdx.x, lane = t & 63, wv = t >> 6;
  const int q = lane >> 4, n15 = lane & 15;
  const int base = blockIdx.x * 256;

  // per-et edge metadata in registers
  int pev[4]; float angv[4]; int dkv[4];
  #pragma unroll
  for (int et = 0; et < 4; et++){
    int gi = base + wv * 64 + et * 16 + n15;
    int gic = gi < NEDGES ? gi : NEDGES - 1;
    pev[et] = perm[gic];
  }
  #pragma unroll
  for (int et = 0; et < 4; et++){
    angv[et] = ang[pev[et]];
    dkv[et]  = ei[NEDGES + pev[et]];
  }

  { // stage own row t: own et == q (row t = base + wv*64 + q*16 + n15)
    int peO = (q == 0) ? pev[0] : (q == 1) ? pev[1] : (q == 2) ? pev[2] : pev[3];
    int dO  = (q == 0) ? dkv[0] : (q == 1) ? dkv[1] : (q == 2) ? dkv[2] : dkv[3];
    int sO  = ei[peO];
    int rs = t & RSM;
    f16* hp = &Hn[t << RSH];
    if (FP32IN){
      const float* xf = (const float*)xin;
      const float4* pd = (const float4*)(xf + (long)dO * 16);
      const float4* ps = (const float4*)(xf + (long)sO * 16);
      #pragma unroll
      for (int c = 0; c < 4; c++){
        const float4* pp = (c < 2) ? pd : ps;
        float4 va = pp[(c & 1) * 2];
        float4 vb = pp[(c & 1) * 2 + 1];
        float xv8[8] = {va.x, va.y, va.z, va.w, vb.x, vb.y, vb.z, vb.w};
        f16x8 hi8, lo8;
        #pragma unroll
        for (int k = 0; k < 8; k++){
          float v = xv8[k];
          f16 h = (f16)v;
          hi8[k] = h;
          lo8[k] = (f16)(v - (float)h);
        }
        *(f16x8*)&hp[(c ^ rs) << 3]       = hi8;
        *(f16x8*)&hp[((c + 4) ^ rs) << 3] = lo8;
      }
    } else {
      const f16* xh = (const f16*)xin;
      f16x8 r0 = *(const f16x8*)&xh[(long)dO * 16];
      f16x8 r1 = *(const f16x8*)&xh[(long)dO * 16 + 8];
      f16x8 r2 = *(const f16x8*)&xh[(long)sO * 16];
      f16x8 r3 = *(const f16x8*)&xh[(long)sO * 16 + 8];
      *(f16x8*)&hp[(0 ^ rs) << 3] = r0;
      *(f16x8*)&hp[(1 ^ rs) << 3] = r1;
      *(f16x8*)&hp[(2 ^ rs) << 3] = r2;
      *(f16x8*)&hp[(3 ^ rs) << 3] = r3;
    }
  }
  // no __syncthreads(): all LDS reads below are of this wave's own rows

  float4 wang = *(const float4*)&w0f[32 * 16 + 4 * q];

  f32x4 C[4];
  for (int lay = 0; lay < 6; lay++){
    const float* bp = (lay == 0) ? b0 : &bh[(lay - 1) * 16];
    float4 b4 = *(const float4*)&bp[4 * q];
    #pragma unroll
    for (int et = 0; et < 4; et++){
      C[et] = (f32x4){b4.x, b4.y, b4.z, b4.w};
      if (lay == 0){
        float a = angv[et];
        C[et][0] += a * wang.x; C[et][1] += a * wang.y;
        C[et][2] += a * wang.z; C[et][3] += a * wang.w;
      }
    }
    const int nst = (lay == 0) ? (FP32IN ? 3 : 2) : 2;
    #pragma unroll 3
    for (int st = 0; st < nst; st++){
      int fr, cb;
      if (lay == 0){
        if (FP32IN){ fr = (st == 2) ? 1 : 0; cb = (st == 1) ? 4 : 0; }
        else       { fr = st; cb = 0; }
      }
      else { fr = 2 + 2 * (lay - 1) + st; cb = 0; }
      f16x8 Af = *(const f16x8*)&gfn[(fr << 9) + (lane << 3)];
      int c = cb + q;
      #pragma unroll
      for (int et = 0; et < 4; et++){
        int r = wv * 64 + et * 16 + n15;
        f16x8 Bf = *(const f16x8*)&Hn[(r << RSH) + ((c ^ (r & RSM)) << 3)];
        C[et] = __builtin_amdgcn_mfma_f32_16x16x32_f16(Af, Bf, C[et], 0, 0, 0);
      }
    }
    if (lay < 5){
      #pragma unroll
      for (int et = 0; et < 4; et++){
        int r = wv * 64 + et * 16 + n15;
        f16x4 hi4, lo4;
        #pragma unroll
        for (int reg = 0; reg < 4; reg++){
          float v = fmaxf(C[et][reg], 0.f);
          f16 h = (f16)v;
          hi4[reg] = h;
          lo4[reg] = (f16)(v - (float)h);
        }
        int ch = 4 * q;
        *(f16x4*)&Hn[(r << RSH) + ((((ch >> 3) ^ (r & RSM)) << 3) | (ch & 7))] = hi4;
        int cl = 16 + 4 * q;
        *(f16x4*)&Hn[(r << RSH) + ((((cl >> 3) ^ (r & RSM)) << 3) | (cl & 7))] = lo4;
      }
    } else {
      #pragma unroll
      for (int et = 0; et < 4; et++){
        int li = wv * 64 + et * 16 + n15;
        bool valid = (base + li) < NEDGES;
        int dk = valid ? dkv[et] : -1;
        bool sm[4];
        int o = 1;
        #pragma unroll
        for (int k2 = 0; k2 < 4; k2++, o <<= 1){
          int dn = __shfl_down(dk, o);
          sm[k2] = (n15 + o < 16) && (dn == dk);
        }
        int dprev = __shfl_up(dk, 1);
        bool head = valid && ((n15 == 0) || (dprev != dk));
        #pragma unroll
        for (int reg = 0; reg < 4; reg++){
          float v = valid ? fmaxf(C[et][reg], 0.f) : 0.f;
          o = 1;
          #pragma unroll
          for (int k2 = 0; k2 < 4; k2++, o <<= 1){
            float vn = __shfl_down(v, o);
            if (sm[k2]) v += vn;
          }
          if (head) atomicAdd(&agg[(long)dk * 16 + 4 * q + reg], v);
        }
      }
    }
  }
}

// ---- finalize: xh[n] = f16( agg[n] / max(deg,1) ); re-zeroes agg in place ----
__global__ __launch_bounds__(256) void node_finh(
    float* __restrict__ agg, const int* __restrict__ rowptr, f16* __restrict__ xh)
{
  int n = blockIdx.x * 256 + threadIdx.x;
  if (n >= NNODES) return;
  float inv = 1.f / fmaxf((float)(rowptr[n+1] - rowptr[n]), 1.f);
  float4* ap = (float4*)&agg[(long)n * 16];
  float4 z = {0.f, 0.f, 0.f, 0.f};
  f16x8 o0, o1;
  #pragma unroll
  for (int k = 0; k < 2; k++){
    float4 v = ap[k];
    o0[4*k] = (f16)(v.x*inv); o0[4*k+1] = (f16)(v.y*inv);
    o0[4*k+2] = (f16)(v.z*inv); o0[4*k+3] = (f16)(v.w*inv);
    ap[k] = z;
  }
  #pragma unroll
  for (int k = 0; k < 2; k++){
    float4 v = ap[2+k];
    o1[4*k] = (f16)(v.x*inv); o1[4*k+1] = (f16)(v.y*inv);
    o1[4*k+2] = (f16)(v.z*inv); o1[4*k+3] = (f16)(v.w*inv);
    ap[2+k] = z;
  }
  *(f16x8*)&xh[(long)n * 16]     = o0;
  *(f16x8*)&xh[(long)n * 16 + 8] = o1;
}

// ============================================================================
// Fused EdgeConv1+EdgeConv2, BARRIER-FREE, 1 tile (64 edges) per block.
// NATURAL EDGE ORDER: act[e], ei[e], out[e] contiguous; only xh gathers random.
// ef folded into outAcc at conv1 time (linear functional).
// __launch_bounds__(256,5): spill-free (r8 verified: VGPR 48, WRITE 2.6MB,
// 176.5µs). N=6 spills (r7: WRITE 152MB); N=4 leaves occupancy on the table.
// ============================================================================
__global__ __launch_bounds__(256, 5) void ec_mfma(
    const f16* __restrict__ xh1, const f16* __restrict__ xh2,
    const int* __restrict__ ei,
    const float* __restrict__ act, const f16* __restrict__ gf,
    const float* __restrict__ e1wc, const float* __restrict__ e1b0,
    const float* __restrict__ e1bh, const float* __restrict__ e1bc,
    const float* __restrict__ e2b0, const float* __restrict__ e2bh,
    const float* __restrict__ e2wc, const float* __restrict__ e2bc,
    float* __restrict__ outG, float* __restrict__ slacc)
{
  __shared__ __align__(16) f16 Hb[128 * 64];
  __shared__ float sred[4];

  const int t = threadIdx.x;
  const int lane = t & 63;
  const int wv = t >> 6;
  const int q = lane >> 4, n15 = lane & 15;
  const int eidx = (lane >> 1) & 15;      // edge within wave (staging)
  const int fh   = lane >> 5;             // 0: f1 rows, 1: f2 rows
  const int sub  = lane & 1;              // chunk pair selector
  const int myrow = fh * 64 + wv * 16 + eidx;
  const int gebase = blockIdx.x * 64;

  // staging node (f1=[x_d|x_s], f2=[x_s|x_d]); natural edge order, contiguous ei
  const int node = ei[((fh ^ sub) ? 0 : NEDGES) + gebase + wv * 16 + eidx];
  // this lane's output edge (contiguous act read / out write)
  const int e2 = gebase + wv * 16 + n15;
  const float aL = act[e2];

  const int rs = myrow & 7;
  auto store_lds = [&](const f16* __restrict__ xh){
    f16x8 pa0 = *(const f16x8*)&xh[(long)node * 16];
    f16x8 pa1 = *(const f16x8*)&xh[(long)node * 16 + 8];
    f16* hp = &Hb[myrow << 6];
    *(f16x8*)&hp[((2*sub)     ^ rs) << 3] = pa0;
    *(f16x8*)&hp[((2*sub + 1) ^ rs) << 3] = pa1;
    if (sub){
      f16x8 z = {};
      *(f16x8*)&hp[(6 ^ rs) << 3] = z;
      *(f16x8*)&hp[(7 ^ rs) << 3] = z;
    }
  };

  float side = 0.f;
  float outAcc = 0.f;   // accumulates ef·wb at mode 2, then fe·wa at mode 3

  auto layer = [&](int lay, const float* bias, int nks, int mode){
    const int nEt = (mode == 2) ? 1 : 2;
    f32x4 C[3][2];
    #pragma unroll
    for (int wt = 0; wt < 3; wt++){
      float4 b4 = *(const float4*)&bias[wt*16 + 4*q];
      C[wt][0] = (f32x4){b4.x, b4.y, b4.z, b4.w};
      C[wt][1] = C[wt][0];
    }
    for (int ks = 0; ks < nks; ks++){
      int c = ks*4 + q;
      f16x8 Af[3];
      #pragma unroll
      for (int wt = 0; wt < 3; wt++)
        Af[wt] = *(const f16x8*)&gf[((((lay*2 + ks)*3) + wt) << 9) + (lane << 3)];
      for (int et = 0; et < nEt; et++){
        int r = (et << 6) + wv*16 + n15;
        f16x8 Bf = *(const f16x8*)&Hb[(r << 6) + ((c ^ (r & 7)) << 3)];
        #pragma unroll
        for (int wt = 0; wt < 3; wt++)
          C[wt][et] = __builtin_amdgcn_mfma_f32_16x16x32_f16(Af[wt], Bf, C[wt][et], 0, 0, 0);
      }
    }
    if (mode == 0){
      #pragma unroll
      for (int et = 0; et < 2; et++){
        int r = (et << 6) + wv*16 + n15;
        #pragma unroll
        for (int wt = 0; wt < 3; wt++){
          f16x4 pk;
          #pragma unroll
          for (int reg = 0; reg < 4; reg++) pk[reg] = (f16)fmaxf(C[wt][et][reg], 0.f);
          int col = wt*16 + 4*q;
          *(f16x4*)&Hb[(r << 6) + ((((col >> 3) ^ (r & 7)) << 3) | (col & 7))] = pk;
        }
      }
    } else if (mode == 1){
      int r = wv*16 + n15;
      #pragma unroll
      for (int wt = 0; wt < 3; wt++){
        f16x4 pk;
        #pragma unroll
        for (int reg = 0; reg < 4; reg++){
          float v1 = fmaxf(C[wt][0][reg], 0.f);
          float v2 = fmaxf(C[wt][1][reg], 0.f);
          float dd = v1 - v2; side += dd * dd;
          pk[reg] = (f16)(0.5f * (v1 + v2));
        }
        int col = wt*16 + 4*q;
        *(f16x4*)&Hb[(r << 6) + ((((col >> 3) ^ (r & 7)) << 3) | (col & 7))] = pk;
      }
    } else if (mode == 2){
      // ef = C + aL*wr; consumed only as sum(ef * e2wc[48..96]) -> fold now
      #pragma unroll
      for (int wt = 0; wt < 3; wt++){
        float4 wr = *(const float4*)&e1wc[2304 + wt*16 + 4*q];
        float4 wb = *(const float4*)&e2wc[48 + wt*16 + 4*q];
        outAcc += (C[wt][0][0] + aL * wr.x) * wb.x
                + (C[wt][0][1] + aL * wr.y) * wb.y
                + (C[wt][0][2] + aL * wr.z) * wb.z
                + (C[wt][0][3] + aL * wr.w) * wb.w;
      }
    } else {
      #pragma unroll
      for (int wt = 0; wt < 3; wt++){
        float4 wa = *(const float4*)&e2wc[wt*16 + 4*q];
        float av[4] = {wa.x, wa.y, wa.z, wa.w};
        #pragma unroll
        for (int reg = 0; reg < 4; reg++){
          float v1 = fmaxf(C[wt][0][reg], 0.f);
          float v2 = fmaxf(C[wt][1][reg], 0.f);
          float dd = v1 - v2; side += dd * dd;
          float fe = 0.5f * (v1 + v2);
          outAcc += fe * av[reg];
        }
      }
    }
  };

  // stage conv1 input (wave-private, no barrier)
  store_lds(xh1);

  // ---- EdgeConv1 ----
  layer(0, e1b0,        1, 0);
  layer(1, e1bh + 0*48, 2, 0);
  layer(2, e1bh + 1*48, 2, 0);
  layer(3, e1bh + 2*48, 2, 0);
  layer(4, e1bh + 3*48, 2, 0);
  layer(5, e1bh + 4*48, 2, 1);
  layer(6, e1bc,        2, 2);   // ef·wb folded into outAcc

  // restage same buffer with conv2 input (wave-private, in-order DS; xh2 L2-hot)
  store_lds(xh2);

  // ---- EdgeConv2 ----
  layer(7,  e2b0,        1, 0);
  layer(8,  e2bh + 0*48, 2, 0);
  layer(9,  e2bh + 1*48, 2, 0);
  layer(10, e2bh + 2*48, 2, 0);
  layer(11, e2bh + 3*48, 2, 0);
  layer(12, e2bh + 4*48, 2, 3);  // fe·wa into outAcc

  {
    float v = outAcc;
    v += __shfl_xor(v, 16);
    v += __shfl_xor(v, 32);
    if (lane < 16) outG[e2] = v + e2bc[0];   // contiguous write
  }

  // side-loss: one atomic per block
  float sv = side;
  #pragma unroll
  for (int off = 32; off; off >>= 1) sv += __shfl_down(sv, off);
  if (lane == 0) sred[wv] = sv;
  __syncthreads();
  if (t == 0) atomicAdd(slacc, sred[0] + sred[1] + sred[2] + sred[3]);
}

// ================= launch ==================
extern "C" void kernel_launch(void* const* d_in, const int* in_sizes, int n_in,
                              void* d_out, int out_size, void* d_ws, size_t ws_size,
                              hipStream_t stream)
{
  if (n_in < 25) return;
  if (ws_size < (size_t)WS_NEED_FLOATS * sizeof(float)) return;

  const float* nf  = (const float*)d_in[0];
  const int*   ei  = (const int*)d_in[1];
  const float* ang = (const float*)d_in[2];
  const float* act = (const float*)d_in[4];
  const float* nc1_w0 = (const float*)d_in[5];
  const float* nc1_b0 = (const float*)d_in[6];
  const float* nc1_wh = (const float*)d_in[7];
  const float* nc1_bh = (const float*)d_in[8];
  const float* nc2_w0 = (const float*)d_in[9];
  const float* nc2_b0 = (const float*)d_in[10];
  const float* nc2_wh = (const float*)d_in[11];
  const float* nc2_bh = (const float*)d_in[12];
  const float* e1w0 = (const float*)d_in[13];
  const float* e1b0 = (const float*)d_in[14];
  const float* e1wh = (const float*)d_in[15];
  const float* e1bh = (const float*)d_in[16];
  const float* e1wc = (const float*)d_in[17];
  const float* e1bc = (const float*)d_in[18];
  const float* e2w0 = (const float*)d_in[19];
  const float* e2b0 = (const float*)d_in[20];
  const float* e2wh = (const float*)d_in[21];
  const float* e2bh = (const float*)d_in[22];
  const float* e2wc = (const float*)d_in[23];
  const float* e2bc = (const float*)d_in[24];

  float* ws  = (float*)d_ws;
  float* out = (float*)d_out;

  f16* xh1    = (f16*)(ws + OX1);
  f16* xh2    = (f16*)(ws + OX2);
  float* agg  = ws + OAGG;
  int* rowptr = (int*)(ws + OROW);
  int* deg    = (int*)(ws + ODEG);
  f16* gf     = (f16*)(ws + OGF);
  f16* gfn    = gf + 39936;
  int* bsum   = (int*)(ws + OSCAN);
  int* boff   = bsum + 512;
  int* perm   = (int*)(ws + OPERM);
  float* sl   = ws + OSL;

  const int eb  = (NEDGES + 255) / 256;
  const int nbN = (NNODES + 255) / 256;
  const int pfb = (39936 + 255) / 256;
  const int pnb = (12288 + 255) / 256;

  (void)hipMemsetAsync(deg, 0, (size_t)NNODES * sizeof(int), stream);
  (void)hipMemsetAsync(sl, 0, sizeof(float), stream);

  hipLaunchKernelGGL(count_deg, dim3(eb), dim3(256), 0, stream, ei, deg);
  hipLaunchKernelGGL(scan_p1, dim3(NBS), dim3(256), 0, stream, deg, bsum);
  hipLaunchKernelGGL(scan_p2, dim3(1), dim3(512), 0, stream, bsum, boff, rowptr);
  hipLaunchKernelGGL(scan_p3, dim3(NBS), dim3(256), 0, stream, deg, boff, rowptr);
  (void)hipMemsetAsync(deg, 0, (size_t)NNODES * sizeof(int), stream);
  hipLaunchKernelGGL(scatter_perm, dim3(eb), dim3(256), 0, stream, ei, rowptr, deg, perm);

  hipLaunchKernelGGL(prep_wfrag, dim3(pfb), dim3(256), 0, stream,
      e1w0, e1wh, e1wc, e2w0, e2wh, gf);
  hipLaunchKernelGGL(prep_wfrag_nc, dim3(pnb), dim3(256), 0, stream,
      nc1_w0, nc1_wh, nc2_w0, nc2_wh, gfn);

  // NodeConv1: fp32 nf -> agg -> xh1 (node_finh re-zeroes agg for NC2)
  // (agg memset also retires the scan scratch aliased at OSCAN)
  (void)hipMemsetAsync(agg, 0, (size_t)NNODES * 16 * sizeof(float), stream);
  hipLaunchKernelGGL((nc_mfma<true>), dim3(eb), dim3(256), 0, stream,
      (const void*)nf, ei, ang, perm, gfn, nc1_w0, nc1_b0, nc1_bh, agg);
  hipLaunchKernelGGL(node_finh, dim3(nbN), dim3(256), 0, stream, agg, rowptr, xh1);

  // NodeConv2: f16 xh1 -> agg -> xh2
  hipLaunchKernelGGL((nc_mfma<false>), dim3(eb), dim3(256), 0, stream,
      (const void*)xh1, ei, ang, perm, gfn + 12 * 512, nc2_w0, nc2_b0, nc2_bh, agg);
  hipLaunchKernelGGL(node_finh, dim3(nbN), dim3(256), 0, stream, agg, rowptr, xh2);

  // fused EdgeConv1+2: natural edge order, all IO contiguous except xh gathers
  hipLaunchKernelGGL(ec_mfma, dim3(ECNB), dim3(256), 0, stream,
      xh1, xh2, ei, act, gf,
      e1wc, e1b0, e1bh, e1bc, e2b0, e2bh, e2wc, e2bc,
      out, sl);

  hipLaunchKernelGGL(fin_loss, dim3(1), dim3(1), 0, stream, sl, out);
}

// Round 12
// 441.130 us; speedup vs baseline: 1.0887x; 1.0496x over previous
//
#include <hip/hip_runtime.h>

typedef unsigned int u32;
typedef _Float16 f16;
typedef __attribute__((ext_vector_type(8))) _Float16 f16x8;
typedef __attribute__((ext_vector_type(4))) _Float16 f16x4;
typedef __attribute__((ext_vector_type(4))) float f32x4;

#define NNODES 100000
#define NEDGES 600000
#define CC 16
#define HH 48
#define NL 5
#define ECNB 9375                  // 9375 * 64 = 600000 exact (1 tile of 64 edges per block)
#define NBS 391                    // ceil(100000/256) scan blocks

// ---- ws layout (float units), total 4,000,064 floats = 16.0 MB ----
// TIMELINE-aliased regions (r6 lesson: check liveness in TIME, not just ranges):
//   OSCAN/ORANK alias OAGG: bsum/boff/rank live only [count_deg .. scatter_perm];
//   agg's memset and first use are strictly after scatter_perm in stream order.
#define OX1   0                    // xh1 f16
#define OX2   800000               // xh2 f16
#define OAGG  1600000              // agg fp32 [1.6M, 3.2M)
#define OSCAN 1600000              // bsum(512) + boff(512) ints, dead before agg memset
#define ORANK 1601024              // rank[600000] ints, dead before agg memset (ends 2201024)
#define OROW  3200000
#define ODEG  3300032              // deg during CSR build; then gf + gfn (f16)
#define OGF   3300032
#define OPERM 3400032
#define OSL   4000032
#define WS_NEED_FLOATS 4000064

// =================== CSR build ===================
// r12: count_deg saves each edge's within-node arrival rank; scatter_perm
// becomes atomic-free (600K atomics + one 400KB memset deleted). perm content
// identical (within-node order was already race-arbitrary; math order-blind).
__global__ __launch_bounds__(256) void count_deg(const int* __restrict__ ei,
    int* __restrict__ deg, int* __restrict__ rank){
  int e = blockIdx.x * 256 + threadIdx.x;
  if (e >= NEDGES) return;
  rank[e] = atomicAdd(&deg[ei[NEDGES + e]], 1);
}

// ---- multi-block exclusive scan of deg -> rowptr ----
__global__ __launch_bounds__(256) void scan_p1(const int* __restrict__ deg, int* __restrict__ bsum){
  __shared__ int red[256];
  int b = blockIdx.x, t = threadIdx.x;
  int i = b * 256 + t;
  red[t] = (i < NNODES) ? deg[i] : 0;
  __syncthreads();
  for (int off = 128; off; off >>= 1){
    if (t < off) red[t] += red[t + off];
    __syncthreads();
  }
  if (t == 0) bsum[b] = red[0];
}

__global__ __launch_bounds__(512) void scan_p2(const int* __restrict__ bsum,
    int* __restrict__ boff, int* __restrict__ rowptr){
  __shared__ int s[512];
  int t = threadIdx.x;
  s[t] = (t < NBS) ? bsum[t] : 0;
  __syncthreads();
  for (int off = 1; off < 512; off <<= 1){
    int v = (t >= off) ? s[t - off] : 0;
    __syncthreads();
    s[t] += v;
    __syncthreads();
  }
  if (t < NBS) boff[t] = (t == 0) ? 0 : s[t - 1];
  if (t == 0) rowptr[NNODES] = s[NBS - 1];
}

__global__ __launch_bounds__(256) void scan_p3(const int* __restrict__ deg,
    const int* __restrict__ boff, int* __restrict__ rowptr){
  __shared__ int s[256];
  int b = blockIdx.x, t = threadIdx.x;
  int i = b * 256 + t;
  int d = (i < NNODES) ? deg[i] : 0;
  s[t] = d;
  __syncthreads();
  for (int off = 1; off < 256; off <<= 1){
    int v = (t >= off) ? s[t - off] : 0;
    __syncthreads();
    s[t] += v;
    __syncthreads();
  }
  if (i < NNODES) rowptr[i] = boff[b] + s[t] - d;
}

__global__ __launch_bounds__(256) void scatter_perm(const int* __restrict__ ei,
    const int* __restrict__ rowptr, const int* __restrict__ rank, int* __restrict__ perm){
  int e = blockIdx.x * 256 + threadIdx.x;
  if (e >= NEDGES) return;
  perm[rowptr[ei[NEDGES + e]] + rank[e]] = e;
}

// =================== final loss write (ec writes out[] directly) ===================
__global__ void fin_loss(const float* __restrict__ slacc, float* __restrict__ out){
  out[NEDGES] = slacc[0] * (1.0f / 57600000.0f);  // loss = S/(2*48*E)
}

// ============ EC W-fragment precompute (r13-proven) ============
__global__ __launch_bounds__(256) void prep_wfrag(
    const float* __restrict__ e1w0, const float* __restrict__ e1wh, const float* __restrict__ e1wc,
    const float* __restrict__ e2w0, const float* __restrict__ e2wh, f16* __restrict__ gf)
{
  int idx = blockIdx.x * 256 + threadIdx.x;
  if (idx >= 39936) return;
  int j = idx & 7, lane = (idx >> 3) & 63, f = idx >> 9;
  int wt = f % 3, ksl = f / 3;
  int ks = ksl & 1, lay = ksl >> 1;
  int k = ks * 32 + ((lane >> 4) << 3) + j;
  int m = wt * 16 + (lane & 15);
  const float* w; int Kl;
  if (lay == 0){ w = e1w0; Kl = 32; }
  else if (lay <= 5){ w = e1wh + (lay - 1) * 2304; Kl = 48; }
  else if (lay == 6){ w = e1wc; Kl = 48; }
  else if (lay == 7){ w = e2w0; Kl = 32; }
  else { w = e2wh + (lay - 8) * 2304; Kl = 48; }
  gf[idx] = (k < Kl) ? (f16)w[k * 48 + m] : (f16)0.f;
}

// ============ NC W-fragments, SPLIT precision (r20-proven) ============
__global__ __launch_bounds__(256) void prep_wfrag_nc(
    const float* __restrict__ n1w0, const float* __restrict__ n1wh,
    const float* __restrict__ n2w0, const float* __restrict__ n2wh,
    f16* __restrict__ gfn)
{
  int idx = blockIdx.x * 256 + threadIdx.x;
  if (idx >= 24 * 512) return;
  int j = idx & 7, lane = (idx >> 3) & 63, f = idx >> 9;
  int conv = f / 12, slot = f % 12;
  int kq = ((lane >> 4) << 3) + j;
  int m = lane & 15;
  const float* w0 = conv ? n2w0 : n1w0;
  const float* wh = conv ? n2wh : n1wh;
  float val;
  bool wantLo;
  if (slot <= 1){
    val = w0[kq * 16 + m];
    wantLo = (slot == 1);
  } else {
    int l = (slot - 2) >> 1;
    bool isB = (slot - 2) & 1;
    const float* wl = wh + l * 256;
    if (!isB){ val = wl[(kq & 15) * 16 + m]; wantLo = false; }
    else if (kq < 16){ val = wl[kq * 16 + m]; wantLo = true; }
    else { gfn[idx] = (f16)0.f; return; }
  }
  f16 hi = (f16)val;
  gfn[idx] = wantLo ? (f16)(val - (float)hi) : hi;
}

// ============================================================================
// NodeConv via MFMA, SPLIT-f16 (r20-proven math), BARRIER-FREE.
// __launch_bounds__(256,4): spill-free regime (r4 calibration).
// ============================================================================
template<bool FP32IN>
__global__ __launch_bounds__(256, 4) void nc_mfma(
    const void* __restrict__ xin, const int* __restrict__ ei,
    const float* __restrict__ ang, const int* __restrict__ perm,
    const f16* __restrict__ gfn,
    const float* __restrict__ w0f,
    const float* __restrict__ b0, const float* __restrict__ bh,
    float* __restrict__ agg)
{
  constexpr int RW  = FP32IN ? 64 : 32;   // row width in f16
  constexpr int RSH = FP32IN ? 6  : 5;    // row shift
  constexpr int RSM = FP32IN ? 7  : 3;    // chunk swizzle mask
  __shared__ __align__(16) f16 Hn[256 * RW];

  const int t = threadIdx.x, lane = t & 63, wv = t >> 6;
  const int q = lane >> 4, n15 = lane & 15;
  const int base = blockIdx.x * 256;

  // per-et edge metadata in registers
  int pev[4]; float angv[4]; int dkv[4];
  #pragma unroll
  for (int et = 0; et < 4; et++){
    int gi = base + wv * 64 + et * 16 + n15;
    int gic = gi < NEDGES ? gi : NEDGES - 1;
    pev[et] = perm[gic];
  }
  #pragma unroll
  for (int et = 0; et < 4; et++){
    angv[et] = ang[pev[et]];
    dkv[et]  = ei[NEDGES + pev[et]];
  }

  { // stage own row t: own et == q (row t = base + wv*64 + q*16 + n15)
    int peO = (q == 0) ? pev[0] : (q == 1) ? pev[1] : (q == 2) ? pev[2] : pev[3];
    int dO  = (q == 0) ? dkv[0] : (q == 1) ? dkv[1] : (q == 2) ? dkv[2] : dkv[3];
    int sO  = ei[peO];
    int rs = t & RSM;
    f16* hp = &Hn[t << RSH];
    if (FP32IN){
      const float* xf = (const float*)xin;
      const float4* pd = (const float4*)(xf + (long)dO * 16);
      const float4* ps = (const float4*)(xf + (long)sO * 16);
      #pragma unroll
      for (int c = 0; c < 4; c++){
        const float4* pp = (c < 2) ? pd : ps;
        float4 va = pp[(c & 1) * 2];
        float4 vb = pp[(c & 1) * 2 + 1];
        float xv8[8] = {va.x, va.y, va.z, va.w, vb.x, vb.y, vb.z, vb.w};
        f16x8 hi8, lo8;
        #pragma unroll
        for (int k = 0; k < 8; k++){
          float v = xv8[k];
          f16 h = (f16)v;
          hi8[k] = h;
          lo8[k] = (f16)(v - (float)h);
        }
        *(f16x8*)&hp[(c ^ rs) << 3]       = hi8;
        *(f16x8*)&hp[((c + 4) ^ rs) << 3] = lo8;
      }
    } else {
      const f16* xh = (const f16*)xin;
      f16x8 r0 = *(const f16x8*)&xh[(long)dO * 16];
      f16x8 r1 = *(const f16x8*)&xh[(long)dO * 16 + 8];
      f16x8 r2 = *(const f16x8*)&xh[(long)sO * 16];
      f16x8 r3 = *(const f16x8*)&xh[(long)sO * 16 + 8];
      *(f16x8*)&hp[(0 ^ rs) << 3] = r0;
      *(f16x8*)&hp[(1 ^ rs) << 3] = r1;
      *(f16x8*)&hp[(2 ^ rs) << 3] = r2;
      *(f16x8*)&hp[(3 ^ rs) << 3] = r3;
    }
  }
  // no __syncthreads(): all LDS reads below are of this wave's own rows

  float4 wang = *(const float4*)&w0f[32 * 16 + 4 * q];

  f32x4 C[4];
  for (int lay = 0; lay < 6; lay++){
    const float* bp = (lay == 0) ? b0 : &bh[(lay - 1) * 16];
    float4 b4 = *(const float4*)&bp[4 * q];
    #pragma unroll
    for (int et = 0; et < 4; et++){
      C[et] = (f32x4){b4.x, b4.y, b4.z, b4.w};
      if (lay == 0){
        float a = angv[et];
        C[et][0] += a * wang.x; C[et][1] += a * wang.y;
        C[et][2] += a * wang.z; C[et][3] += a * wang.w;
      }
    }
    const int nst = (lay == 0) ? (FP32IN ? 3 : 2) : 2;
    #pragma unroll 3
    for (int st = 0; st < nst; st++){
      int fr, cb;
      if (lay == 0){
        if (FP32IN){ fr = (st == 2) ? 1 : 0; cb = (st == 1) ? 4 : 0; }
        else       { fr = st; cb = 0; }
      }
      else { fr = 2 + 2 * (lay - 1) + st; cb = 0; }
      f16x8 Af = *(const f16x8*)&gfn[(fr << 9) + (lane << 3)];
      int c = cb + q;
      #pragma unroll
      for (int et = 0; et < 4; et++){
        int r = wv * 64 + et * 16 + n15;
        f16x8 Bf = *(const f16x8*)&Hn[(r << RSH) + ((c ^ (r & RSM)) << 3)];
        C[et] = __builtin_amdgcn_mfma_f32_16x16x32_f16(Af, Bf, C[et], 0, 0, 0);
      }
    }
    if (lay < 5){
      #pragma unroll
      for (int et = 0; et < 4; et++){
        int r = wv * 64 + et * 16 + n15;
        f16x4 hi4, lo4;
        #pragma unroll
        for (int reg = 0; reg < 4; reg++){
          float v = fmaxf(C[et][reg], 0.f);
          f16 h = (f16)v;
          hi4[reg] = h;
          lo4[reg] = (f16)(v - (float)h);
        }
        int ch = 4 * q;
        *(f16x4*)&Hn[(r << RSH) + ((((ch >> 3) ^ (r & RSM)) << 3) | (ch & 7))] = hi4;
        int cl = 16 + 4 * q;
        *(f16x4*)&Hn[(r << RSH) + ((((cl >> 3) ^ (r & RSM)) << 3) | (cl & 7))] = lo4;
      }
    } else {
      #pragma unroll
      for (int et = 0; et < 4; et++){
        int li = wv * 64 + et * 16 + n15;
        bool valid = (base + li) < NEDGES;
        int dk = valid ? dkv[et] : -1;
        bool sm[4];
        int o = 1;
        #pragma unroll
        for (int k2 = 0; k2 < 4; k2++, o <<= 1){
          int dn = __shfl_down(dk, o);
          sm[k2] = (n15 + o < 16) && (dn == dk);
        }
        int dprev = __shfl_up(dk, 1);
        bool head = valid && ((n15 == 0) || (dprev != dk));
        #pragma unroll
        for (int reg = 0; reg < 4; reg++){
          float v = valid ? fmaxf(C[et][reg], 0.f) : 0.f;
          o = 1;
          #pragma unroll
          for (int k2 = 0; k2 < 4; k2++, o <<= 1){
            float vn = __shfl_down(v, o);
            if (sm[k2]) v += vn;
          }
          if (head) atomicAdd(&agg[(long)dk * 16 + 4 * q + reg], v);
        }
      }
    }
  }
}

// ---- finalize: xh[n] = f16( agg[n] / max(deg,1) ); re-zeroes agg in place ----
__global__ __launch_bounds__(256) void node_finh(
    float* __restrict__ agg, const int* __restrict__ rowptr, f16* __restrict__ xh)
{
  int n = blockIdx.x * 256 + threadIdx.x;
  if (n >= NNODES) return;
  float inv = 1.f / fmaxf((float)(rowptr[n+1] - rowptr[n]), 1.f);
  float4* ap = (float4*)&agg[(long)n * 16];
  float4 z = {0.f, 0.f, 0.f, 0.f};
  f16x8 o0, o1;
  #pragma unroll
  for (int k = 0; k < 2; k++){
    float4 v = ap[k];
    o0[4*k] = (f16)(v.x*inv); o0[4*k+1] = (f16)(v.y*inv);
    o0[4*k+2] = (f16)(v.z*inv); o0[4*k+3] = (f16)(v.w*inv);
    ap[k] = z;
  }
  #pragma unroll
  for (int k = 0; k < 2; k++){
    float4 v = ap[2+k];
    o1[4*k] = (f16)(v.x*inv); o1[4*k+1] = (f16)(v.y*inv);
    o1[4*k+2] = (f16)(v.z*inv); o1[4*k+3] = (f16)(v.w*inv);
    ap[2+k] = z;
  }
  *(f16x8*)&xh[(long)n * 16]     = o0;
  *(f16x8*)&xh[(long)n * 16 + 8] = o1;
}

// ============================================================================
// Fused EdgeConv1+EdgeConv2, BARRIER-FREE, 1 tile (64 edges) per block.
// NATURAL EDGE ORDER: act[e], ei[e], out[e] contiguous; only xh gathers random.
// ef folded into outAcc at conv1 time (linear functional).
// __launch_bounds__(256,5): spill-free (r8/r11 verified: VGPR 48, WRITE 2.6MB).
// r12: xh2 gather ISSUED after layer 3 (regs live across layers 4-6 only, ~4K
// cyc of latency cover) instead of at the conv boundary where its ~200-900cyc
// latency was fully exposed once per wave. LDS write stays after layer 6
// (conv1's last Hb read); per-wave in-order DS keeps the restage safe.
// REVERT CRITERION: WRITE_SIZE > 10MB => spilled => undo next round.
// ============================================================================
__global__ __launch_bounds__(256, 5) void ec_mfma(
    const f16* __restrict__ xh1, const f16* __restrict__ xh2,
    const int* __restrict__ ei,
    const float* __restrict__ act, const f16* __restrict__ gf,
    const float* __restrict__ e1wc, const float* __restrict__ e1b0,
    const float* __restrict__ e1bh, const float* __restrict__ e1bc,
    const float* __restrict__ e2b0, const float* __restrict__ e2bh,
    const float* __restrict__ e2wc, const float* __restrict__ e2bc,
    float* __restrict__ outG, float* __restrict__ slacc)
{
  __shared__ __align__(16) f16 Hb[128 * 64];
  __shared__ float sred[4];

  const int t = threadIdx.x;
  const int lane = t & 63;
  const int wv = t >> 6;
  const int q = lane >> 4, n15 = lane & 15;
  const int eidx = (lane >> 1) & 15;      // edge within wave (staging)
  const int fh   = lane >> 5;             // 0: f1 rows, 1: f2 rows
  const int sub  = lane & 1;              // chunk pair selector
  const int myrow = fh * 64 + wv * 16 + eidx;
  const int gebase = blockIdx.x * 64;

  // staging node (f1=[x_d|x_s], f2=[x_s|x_d]); natural edge order, contiguous ei
  const int node = ei[((fh ^ sub) ? 0 : NEDGES) + gebase + wv * 16 + eidx];
  // this lane's output edge (contiguous act read / out write)
  const int e2 = gebase + wv * 16 + n15;
  const float aL = act[e2];

  const int rs = myrow & 7;
  auto write_lds = [&](f16x8 pa0, f16x8 pa1){
    f16* hp = &Hb[myrow << 6];
    *(f16x8*)&hp[((2*sub)     ^ rs) << 3] = pa0;
    *(f16x8*)&hp[((2*sub + 1) ^ rs) << 3] = pa1;
    if (sub){
      f16x8 z = {};
      *(f16x8*)&hp[(6 ^ rs) << 3] = z;
      *(f16x8*)&hp[(7 ^ rs) << 3] = z;
    }
  };

  float side = 0.f;
  float outAcc = 0.f;   // accumulates ef·wb at mode 2, then fe·wa at mode 3

  auto layer = [&](int lay, const float* bias, int nks, int mode){
    const int nEt = (mode == 2) ? 1 : 2;
    f32x4 C[3][2];
    #pragma unroll
    for (int wt = 0; wt < 3; wt++){
      float4 b4 = *(const float4*)&bias[wt*16 + 4*q];
      C[wt][0] = (f32x4){b4.x, b4.y, b4.z, b4.w};
      C[wt][1] = C[wt][0];
    }
    for (int ks = 0; ks < nks; ks++){
      int c = ks*4 + q;
      f16x8 Af[3];
      #pragma unroll
      for (int wt = 0; wt < 3; wt++)
        Af[wt] = *(const f16x8*)&gf[((((lay*2 + ks)*3) + wt) << 9) + (lane << 3)];
      for (int et = 0; et < nEt; et++){
        int r = (et << 6) + wv*16 + n15;
        f16x8 Bf = *(const f16x8*)&Hb[(r << 6) + ((c ^ (r & 7)) << 3)];
        #pragma unroll
        for (int wt = 0; wt < 3; wt++)
          C[wt][et] = __builtin_amdgcn_mfma_f32_16x16x32_f16(Af[wt], Bf, C[wt][et], 0, 0, 0);
      }
    }
    if (mode == 0){
      #pragma unroll
      for (int et = 0; et < 2; et++){
        int r = (et << 6) + wv*16 + n15;
        #pragma unroll
        for (int wt = 0; wt < 3; wt++){
          f16x4 pk;
          #pragma unroll
          for (int reg = 0; reg < 4; reg++) pk[reg] = (f16)fmaxf(C[wt][et][reg], 0.f);
          int col = wt*16 + 4*q;
          *(f16x4*)&Hb[(r << 6) + ((((col >> 3) ^ (r & 7)) << 3) | (col & 7))] = pk;
        }
      }
    } else if (mode == 1){
      int r = wv*16 + n15;
      #pragma unroll
      for (int wt = 0; wt < 3; wt++){
        f16x4 pk;
        #pragma unroll
        for (int reg = 0; reg < 4; reg++){
          float v1 = fmaxf(C[wt][0][reg], 0.f);
          float v2 = fmaxf(C[wt][1][reg], 0.f);
          float dd = v1 - v2; side += dd * dd;
          pk[reg] = (f16)(0.5f * (v1 + v2));
        }
        int col = wt*16 + 4*q;
        *(f16x4*)&Hb[(r << 6) + ((((col >> 3) ^ (r & 7)) << 3) | (col & 7))] = pk;
      }
    } else if (mode == 2){
      // ef = C + aL*wr; consumed only as sum(ef * e2wc[48..96]) -> fold now
      #pragma unroll
      for (int wt = 0; wt < 3; wt++){
        float4 wr = *(const float4*)&e1wc[2304 + wt*16 + 4*q];
        float4 wb = *(const float4*)&e2wc[48 + wt*16 + 4*q];
        outAcc += (C[wt][0][0] + aL * wr.x) * wb.x
                + (C[wt][0][1] + aL * wr.y) * wb.y
                + (C[wt][0][2] + aL * wr.z) * wb.z
                + (C[wt][0][3] + aL * wr.w) * wb.w;
      }
    } else {
      #pragma unroll
      for (int wt = 0; wt < 3; wt++){
        float4 wa = *(const float4*)&e2wc[wt*16 + 4*q];
        float av[4] = {wa.x, wa.y, wa.z, wa.w};
        #pragma unroll
        for (int reg = 0; reg < 4; reg++){
          float v1 = fmaxf(C[wt][0][reg], 0.f);
          float v2 = fmaxf(C[wt][0][reg], 0.f);
          float dd;
          v2 = fmaxf(C[wt][1][reg], 0.f);
          dd = v1 - v2; side += dd * dd;
          float fe = 0.5f * (v1 + v2);
          outAcc += fe * av[reg];
        }
      }
    }
  };

  // stage conv1 input (wave-private, no barrier)
  write_lds(*(const f16x8*)&xh1[(long)node * 16],
            *(const f16x8*)&xh1[(long)node * 16 + 8]);

  // ---- EdgeConv1 ----
  layer(0, e1b0,        1, 0);
  layer(1, e1bh + 0*48, 2, 0);
  layer(2, e1bh + 1*48, 2, 0);
  layer(3, e1bh + 2*48, 2, 0);

  // issue conv2 gather early: latency hides under layers 4-6 (~4K cycles)
  f16x8 pf0 = *(const f16x8*)&xh2[(long)node * 16];
  f16x8 pf1 = *(const f16x8*)&xh2[(long)node * 16 + 8];

  layer(4, e1bh + 3*48, 2, 0);
  layer(5, e1bh + 4*48, 2, 1);
  layer(6, e1bc,        2, 2);   // ef·wb folded into outAcc (last Hb read of conv1)

  // restage same buffer from prefetched regs (wave-private, in-order DS)
  write_lds(pf0, pf1);

  // ---- EdgeConv2 ----
  layer(7,  e2b0,        1, 0);
  layer(8,  e2bh + 0*48, 2, 0);
  layer(9,  e2bh + 1*48, 2, 0);
  layer(10, e2bh + 2*48, 2, 0);
  layer(11, e2bh + 3*48, 2, 0);
  layer(12, e2bh + 4*48, 2, 3);  // fe·wa into outAcc

  {
    float v = outAcc;
    v += __shfl_xor(v, 16);
    v += __shfl_xor(v, 32);
    if (lane < 16) outG[e2] = v + e2bc[0];   // contiguous write
  }

  // side-loss: one atomic per block
  float sv = side;
  #pragma unroll
  for (int off = 32; off; off >>= 1) sv += __shfl_down(sv, off);
  if (lane == 0) sred[wv] = sv;
  __syncthreads();
  if (t == 0) atomicAdd(slacc, sred[0] + sred[1] + sred[2] + sred[3]);
}

// ================= launch ==================
extern "C" void kernel_launch(void* const* d_in, const int* in_sizes, int n_in,
                              void* d_out, int out_size, void* d_ws, size_t ws_size,
                              hipStream_t stream)
{
  if (n_in < 25) return;
  if (ws_size < (size_t)WS_NEED_FLOATS * sizeof(float)) return;

  const float* nf  = (const float*)d_in[0];
  const int*   ei  = (const int*)d_in[1];
  const float* ang = (const float*)d_in[2];
  const float* act = (const float*)d_in[4];
  const float* nc1_w0 = (const float*)d_in[5];
  const float* nc1_b0 = (const float*)d_in[6];
  const float* nc1_wh = (const float*)d_in[7];
  const float* nc1_bh = (const float*)d_in[8];
  const float* nc2_w0 = (const float*)d_in[9];
  const float* nc2_b0 = (const float*)d_in[10];
  const float* nc2_wh = (const float*)d_in[11];
  const float* nc2_bh = (const float*)d_in[12];
  const float* e1w0 = (const float*)d_in[13];
  const float* e1b0 = (const float*)d_in[14];
  const float* e1wh = (const float*)d_in[15];
  const float* e1bh = (const float*)d_in[16];
  const float* e1wc = (const float*)d_in[17];
  const float* e1bc = (const float*)d_in[18];
  const float* e2w0 = (const float*)d_in[19];
  const float* e2b0 = (const float*)d_in[20];
  const float* e2wh = (const float*)d_in[21];
  const float* e2bh = (const float*)d_in[22];
  const float* e2wc = (const float*)d_in[23];
  const float* e2bc = (const float*)d_in[24];

  float* ws  = (float*)d_ws;
  float* out = (float*)d_out;

  f16* xh1    = (f16*)(ws + OX1);
  f16* xh2    = (f16*)(ws + OX2);
  float* agg  = ws + OAGG;
  int* rowptr = (int*)(ws + OROW);
  int* deg    = (int*)(ws + ODEG);
  f16* gf     = (f16*)(ws + OGF);
  f16* gfn    = gf + 39936;
  int* bsum   = (int*)(ws + OSCAN);
  int* boff   = bsum + 512;
  int* rank   = (int*)(ws + ORANK);
  int* perm   = (int*)(ws + OPERM);
  float* sl   = ws + OSL;

  const int eb  = (NEDGES + 255) / 256;
  const int nbN = (NNODES + 255) / 256;
  const int pfb = (39936 + 255) / 256;
  const int pnb = (12288 + 255) / 256;

  (void)hipMemsetAsync(deg, 0, (size_t)NNODES * sizeof(int), stream);
  (void)hipMemsetAsync(sl, 0, sizeof(float), stream);

  hipLaunchKernelGGL(count_deg, dim3(eb), dim3(256), 0, stream, ei, deg, rank);
  hipLaunchKernelGGL(scan_p1, dim3(NBS), dim3(256), 0, stream, deg, bsum);
  hipLaunchKernelGGL(scan_p2, dim3(1), dim3(512), 0, stream, bsum, boff, rowptr);
  hipLaunchKernelGGL(scan_p3, dim3(NBS), dim3(256), 0, stream, deg, boff, rowptr);
  // scatter_perm atomic-free: uses saved rank (second deg memset deleted)
  hipLaunchKernelGGL(scatter_perm, dim3(eb), dim3(256), 0, stream, ei, rowptr, rank, perm);

  hipLaunchKernelGGL(prep_wfrag, dim3(pfb), dim3(256), 0, stream,
      e1w0, e1wh, e1wc, e2w0, e2wh, gf);
  hipLaunchKernelGGL(prep_wfrag_nc, dim3(pnb), dim3(256), 0, stream,
      nc1_w0, nc1_wh, nc2_w0, nc2_wh, gfn);

  // NodeConv1: fp32 nf -> agg -> xh1 (node_finh re-zeroes agg for NC2)
  // (agg memset also retires the scan/rank scratch aliased at OAGG)
  (void)hipMemsetAsync(agg, 0, (size_t)NNODES * 16 * sizeof(float), stream);
  hipLaunchKernelGGL((nc_mfma<true>), dim3(eb), dim3(256), 0, stream,
      (const void*)nf, ei, ang, perm, gfn, nc1_w0, nc1_b0, nc1_bh, agg);
  hipLaunchKernelGGL(node_finh, dim3(nbN), dim3(256), 0, stream, agg, rowptr, xh1);

  // NodeConv2: f16 xh1 -> agg -> xh2
  hipLaunchKernelGGL((nc_mfma<false>), dim3(eb), dim3(256), 0, stream,
      (const void*)xh1, ei, ang, perm, gfn + 12 * 512, nc2_w0, nc2_b0, nc2_bh, agg);
  hipLaunchKernelGGL(node_finh, dim3(nbN), dim3(256), 0, stream, agg, rowptr, xh2);

  // fused EdgeConv1+2: natural edge order, all IO contiguous except xh gathers
  hipLaunchKernelGGL(ec_mfma, dim3(ECNB), dim3(256), 0, stream,
      xh1, xh2, ei, act, gf,
      e1wc, e1b0, e1bh, e1bc, e2b0, e2bh, e2wc, e2bc,
      out, sl);

  hipLaunchKernelGGL(fin_loss, dim3(1), dim3(1), 0, stream, sl, out);
}

// Round 13
// 437.751 us; speedup vs baseline: 1.0971x; 1.0077x over previous
//
#include <hip/hip_runtime.h>

typedef unsigned int u32;
typedef _Float16 f16;
typedef __attribute__((ext_vector_type(8))) _Float16 f16x8;
typedef __attribute__((ext_vector_type(4))) _Float16 f16x4;
typedef __attribute__((ext_vector_type(4))) float f32x4;

#define NNODES 100000
#define NEDGES 600000
#define CC 16
#define HH 48
#define NL 5
#define ECNB 9375                  // 9375 * 64 = 600000 exact (1 tile of 64 edges per block)
#define NBS 391                    // ceil(100000/256) scan blocks

// ---- ws layout (float units), total 4,000,064 floats = 16.0 MB ----
// TIMELINE-aliased regions (r6 lesson: check liveness in TIME, not just ranges):
//   OSCAN/ORANK alias OAGG: bsum/boff/rank live only [count_deg .. scatter_perm];
//   agg's memset and first use are strictly after scatter_perm in stream order.
//   ODSTP aliases OX2: dstp (600K ints) lives [scatter_perm .. nc2]; xh2 is
//   written by finh2, which runs strictly after nc2 completes.
#define OX1   0                    // xh1 f16
#define OX2   800000               // xh2 f16 (after finh2)
#define ODSTP 800000               // dstp int[600K], dead before finh2 writes xh2
#define OAGG  1600000              // agg fp32 [1.6M, 3.2M)
#define OSCAN 1600000              // bsum(512) + boff(512) ints, dead before agg memset
#define ORANK 1601024              // rank[600000] ints, dead before agg memset
#define OROW  3200000
#define ODEG  3300032              // deg during CSR build; then gf + gfn (f16)
#define OGF   3300032
#define OPERM 3400032
#define OSL   4000032
#define WS_NEED_FLOATS 4000064

// =================== CSR build ===================
__global__ __launch_bounds__(256) void count_deg(const int* __restrict__ ei,
    int* __restrict__ deg, int* __restrict__ rank){
  int e = blockIdx.x * 256 + threadIdx.x;
  if (e >= NEDGES) return;
  rank[e] = atomicAdd(&deg[ei[NEDGES + e]], 1);
}

// ---- multi-block exclusive scan of deg -> rowptr ----
__global__ __launch_bounds__(256) void scan_p1(const int* __restrict__ deg, int* __restrict__ bsum){
  __shared__ int red[256];
  int b = blockIdx.x, t = threadIdx.x;
  int i = b * 256 + t;
  red[t] = (i < NNODES) ? deg[i] : 0;
  __syncthreads();
  for (int off = 128; off; off >>= 1){
    if (t < off) red[t] += red[t + off];
    __syncthreads();
  }
  if (t == 0) bsum[b] = red[0];
}

__global__ __launch_bounds__(512) void scan_p2(const int* __restrict__ bsum,
    int* __restrict__ boff, int* __restrict__ rowptr){
  __shared__ int s[512];
  int t = threadIdx.x;
  s[t] = (t < NBS) ? bsum[t] : 0;
  __syncthreads();
  for (int off = 1; off < 512; off <<= 1){
    int v = (t >= off) ? s[t - off] : 0;
    __syncthreads();
    s[t] += v;
    __syncthreads();
  }
  if (t < NBS) boff[t] = (t == 0) ? 0 : s[t - 1];
  if (t == 0) rowptr[NNODES] = s[NBS - 1];
}

__global__ __launch_bounds__(256) void scan_p3(const int* __restrict__ deg,
    const int* __restrict__ boff, int* __restrict__ rowptr){
  __shared__ int s[256];
  int b = blockIdx.x, t = threadIdx.x;
  int i = b * 256 + t;
  int d = (i < NNODES) ? deg[i] : 0;
  s[t] = d;
  __syncthreads();
  for (int off = 1; off < 256; off <<= 1){
    int v = (t >= off) ? s[t - off] : 0;
    __syncthreads();
    s[t] += v;
    __syncthreads();
  }
  if (i < NNODES) rowptr[i] = boff[b] + s[t] - d;
}

// r13: scatter_perm also materializes dstp[pos] (dst per SORTED position).
// nc then reads its segmented-scatter keys dkv as a contiguous level-1 load
// instead of a random ei[perm[i]] gather (level-2) — shortens nc's serial
// dependency chain perm -> ei -> x by one level for dst and its feature gather.
__global__ __launch_bounds__(256) void scatter_perm(const int* __restrict__ ei,
    const int* __restrict__ rowptr, const int* __restrict__ rank,
    int* __restrict__ perm, int* __restrict__ dstp){
  int e = blockIdx.x * 256 + threadIdx.x;
  if (e >= NEDGES) return;
  int d = ei[NEDGES + e];
  int pos = rowptr[d] + rank[e];
  perm[pos] = e;
  dstp[pos] = d;
}

// =================== final loss write (ec writes out[] directly) ===================
__global__ void fin_loss(const float* __restrict__ slacc, float* __restrict__ out){
  out[NEDGES] = slacc[0] * (1.0f / 57600000.0f);  // loss = S/(2*48*E)
}

// ============ EC W-fragment precompute (r13-proven) ============
__global__ __launch_bounds__(256) void prep_wfrag(
    const float* __restrict__ e1w0, const float* __restrict__ e1wh, const float* __restrict__ e1wc,
    const float* __restrict__ e2w0, const float* __restrict__ e2wh, f16* __restrict__ gf)
{
  int idx = blockIdx.x * 256 + threadIdx.x;
  if (idx >= 39936) return;
  int j = idx & 7, lane = (idx >> 3) & 63, f = idx >> 9;
  int wt = f % 3, ksl = f / 3;
  int ks = ksl & 1, lay = ksl >> 1;
  int k = ks * 32 + ((lane >> 4) << 3) + j;
  int m = wt * 16 + (lane & 15);
  const float* w; int Kl;
  if (lay == 0){ w = e1w0; Kl = 32; }
  else if (lay <= 5){ w = e1wh + (lay - 1) * 2304; Kl = 48; }
  else if (lay == 6){ w = e1wc; Kl = 48; }
  else if (lay == 7){ w = e2w0; Kl = 32; }
  else { w = e2wh + (lay - 8) * 2304; Kl = 48; }
  gf[idx] = (k < Kl) ? (f16)w[k * 48 + m] : (f16)0.f;
}

// ============ NC W-fragments, SPLIT precision (r20-proven) ============
__global__ __launch_bounds__(256) void prep_wfrag_nc(
    const float* __restrict__ n1w0, const float* __restrict__ n1wh,
    const float* __restrict__ n2w0, const float* __restrict__ n2wh,
    f16* __restrict__ gfn)
{
  int idx = blockIdx.x * 256 + threadIdx.x;
  if (idx >= 24 * 512) return;
  int j = idx & 7, lane = (idx >> 3) & 63, f = idx >> 9;
  int conv = f / 12, slot = f % 12;
  int kq = ((lane >> 4) << 3) + j;
  int m = lane & 15;
  const float* w0 = conv ? n2w0 : n1w0;
  const float* wh = conv ? n2wh : n1wh;
  float val;
  bool wantLo;
  if (slot <= 1){
    val = w0[kq * 16 + m];
    wantLo = (slot == 1);
  } else {
    int l = (slot - 2) >> 1;
    bool isB = (slot - 2) & 1;
    const float* wl = wh + l * 256;
    if (!isB){ val = wl[(kq & 15) * 16 + m]; wantLo = false; }
    else if (kq < 16){ val = wl[kq * 16 + m]; wantLo = true; }
    else { gfn[idx] = (f16)0.f; return; }
  }
  f16 hi = (f16)val;
  gfn[idx] = wantLo ? (f16)(val - (float)hi) : hi;
}

// ============================================================================
// NodeConv via MFMA, SPLIT-f16 (r20-proven math), BARRIER-FREE.
// __launch_bounds__(256,4): spill-free regime (r4 calibration).
// r13: dkv from contiguous dstp (level-1) instead of random ei[perm] (level-2);
// d-feature gather can issue one dependency level earlier. ang stays a random
// gather (consumed only at layer 0 — plenty of slack). Math identical.
// ============================================================================
template<bool FP32IN>
__global__ __launch_bounds__(256, 4) void nc_mfma(
    const void* __restrict__ xin, const int* __restrict__ ei,
    const float* __restrict__ ang, const int* __restrict__ perm,
    const int* __restrict__ dstp,
    const f16* __restrict__ gfn,
    const float* __restrict__ w0f,
    const float* __restrict__ b0, const float* __restrict__ bh,
    float* __restrict__ agg)
{
  constexpr int RW  = FP32IN ? 64 : 32;   // row width in f16
  constexpr int RSH = FP32IN ? 6  : 5;    // row shift
  constexpr int RSM = FP32IN ? 7  : 3;    // chunk swizzle mask
  __shared__ __align__(16) f16 Hn[256 * RW];

  const int t = threadIdx.x, lane = t & 63, wv = t >> 6;
  const int q = lane >> 4, n15 = lane & 15;
  const int base = blockIdx.x * 256;

  // per-et edge metadata: perm + dstp both CONTIGUOUS (level-1)
  int pev[4]; int dkv[4]; float angv[4];
  #pragma unroll
  for (int et = 0; et < 4; et++){
    int gi = base + wv * 64 + et * 16 + n15;
    int gic = gi < NEDGES ? gi : NEDGES - 1;
    pev[et] = perm[gic];
    dkv[et] = dstp[gic];
  }

  { // stage own row t: own et == q (row t = base + wv*64 + q*16 + n15)
    int peO = (q == 0) ? pev[0] : (q == 1) ? pev[1] : (q == 2) ? pev[2] : pev[3];
    int dO  = (q == 0) ? dkv[0] : (q == 1) ? dkv[1] : (q == 2) ? dkv[2] : dkv[3];
    int rs = t & RSM;
    f16* hp = &Hn[t << RSH];
    if (FP32IN){
      const float* xf = (const float*)xin;
      const float4* pd = (const float4*)(xf + (long)dO * 16);   // level-1 dep
      int sO = ei[peO];                                         // level-2 dep
      const float4* ps = (const float4*)(xf + (long)sO * 16);
      #pragma unroll
      for (int c = 0; c < 4; c++){
        const float4* pp = (c < 2) ? pd : ps;
        float4 va = pp[(c & 1) * 2];
        float4 vb = pp[(c & 1) * 2 + 1];
        float xv8[8] = {va.x, va.y, va.z, va.w, vb.x, vb.y, vb.z, vb.w};
        f16x8 hi8, lo8;
        #pragma unroll
        for (int k = 0; k < 8; k++){
          float v = xv8[k];
          f16 h = (f16)v;
          hi8[k] = h;
          lo8[k] = (f16)(v - (float)h);
        }
        *(f16x8*)&hp[(c ^ rs) << 3]       = hi8;
        *(f16x8*)&hp[((c + 4) ^ rs) << 3] = lo8;
      }
    } else {
      const f16* xh = (const f16*)xin;
      f16x8 r0 = *(const f16x8*)&xh[(long)dO * 16];
      f16x8 r1 = *(const f16x8*)&xh[(long)dO * 16 + 8];
      int sO = ei[peO];
      f16x8 r2 = *(const f16x8*)&xh[(long)sO * 16];
      f16x8 r3 = *(const f16x8*)&xh[(long)sO * 16 + 8];
      *(f16x8*)&hp[(0 ^ rs) << 3] = r0;
      *(f16x8*)&hp[(1 ^ rs) << 3] = r1;
      *(f16x8*)&hp[(2 ^ rs) << 3] = r2;
      *(f16x8*)&hp[(3 ^ rs) << 3] = r3;
    }
  }
  // ang gathers (consumed only at layer 0 — latency covered by staging)
  #pragma unroll
  for (int et = 0; et < 4; et++) angv[et] = ang[pev[et]];
  // no __syncthreads(): all LDS reads below are of this wave's own rows

  float4 wang = *(const float4*)&w0f[32 * 16 + 4 * q];

  f32x4 C[4];
  for (int lay = 0; lay < 6; lay++){
    const float* bp = (lay == 0) ? b0 : &bh[(lay - 1) * 16];
    float4 b4 = *(const float4*)&bp[4 * q];
    #pragma unroll
    for (int et = 0; et < 4; et++){
      C[et] = (f32x4){b4.x, b4.y, b4.z, b4.w};
      if (lay == 0){
        float a = angv[et];
        C[et][0] += a * wang.x; C[et][1] += a * wang.y;
        C[et][2] += a * wang.z; C[et][3] += a * wang.w;
      }
    }
    const int nst = (lay == 0) ? (FP32IN ? 3 : 2) : 2;
    #pragma unroll 3
    for (int st = 0; st < nst; st++){
      int fr, cb;
      if (lay == 0){
        if (FP32IN){ fr = (st == 2) ? 1 : 0; cb = (st == 1) ? 4 : 0; }
        else       { fr = st; cb = 0; }
      }
      else { fr = 2 + 2 * (lay - 1) + st; cb = 0; }
      f16x8 Af = *(const f16x8*)&gfn[(fr << 9) + (lane << 3)];
      int c = cb + q;
      #pragma unroll
      for (int et = 0; et < 4; et++){
        int r = wv * 64 + et * 16 + n15;
        f16x8 Bf = *(const f16x8*)&Hn[(r << RSH) + ((c ^ (r & RSM)) << 3)];
        C[et] = __builtin_amdgcn_mfma_f32_16x16x32_f16(Af, Bf, C[et], 0, 0, 0);
      }
    }
    if (lay < 5){
      #pragma unroll
      for (int et = 0; et < 4; et++){
        int r = wv * 64 + et * 16 + n15;
        f16x4 hi4, lo4;
        #pragma unroll
        for (int reg = 0; reg < 4; reg++){
          float v = fmaxf(C[et][reg], 0.f);
          f16 h = (f16)v;
          hi4[reg] = h;
          lo4[reg] = (f16)(v - (float)h);
        }
        int ch = 4 * q;
        *(f16x4*)&Hn[(r << RSH) + ((((ch >> 3) ^ (r & RSM)) << 3) | (ch & 7))] = hi4;
        int cl = 16 + 4 * q;
        *(f16x4*)&Hn[(r << RSH) + ((((cl >> 3) ^ (r & RSM)) << 3) | (cl & 7))] = lo4;
      }
    } else {
      #pragma unroll
      for (int et = 0; et < 4; et++){
        int li = wv * 64 + et * 16 + n15;
        bool valid = (base + li) < NEDGES;
        int dk = valid ? dkv[et] : -1;
        bool sm[4];
        int o = 1;
        #pragma unroll
        for (int k2 = 0; k2 < 4; k2++, o <<= 1){
          int dn = __shfl_down(dk, o);
          sm[k2] = (n15 + o < 16) && (dn == dk);
        }
        int dprev = __shfl_up(dk, 1);
        bool head = valid && ((n15 == 0) || (dprev != dk));
        #pragma unroll
        for (int reg = 0; reg < 4; reg++){
          float v = valid ? fmaxf(C[et][reg], 0.f) : 0.f;
          o = 1;
          #pragma unroll
          for (int k2 = 0; k2 < 4; k2++, o <<= 1){
            float vn = __shfl_down(v, o);
            if (sm[k2]) v += vn;
          }
          if (head) atomicAdd(&agg[(long)dk * 16 + 4 * q + reg], v);
        }
      }
    }
  }
}

// ---- finalize: xh[n] = f16( agg[n] / max(deg,1) ); re-zeroes agg in place ----
__global__ __launch_bounds__(256) void node_finh(
    float* __restrict__ agg, const int* __restrict__ rowptr, f16* __restrict__ xh)
{
  int n = blockIdx.x * 256 + threadIdx.x;
  if (n >= NNODES) return;
  float inv = 1.f / fmaxf((float)(rowptr[n+1] - rowptr[n]), 1.f);
  float4* ap = (float4*)&agg[(long)n * 16];
  float4 z = {0.f, 0.f, 0.f, 0.f};
  f16x8 o0, o1;
  #pragma unroll
  for (int k = 0; k < 2; k++){
    float4 v = ap[k];
    o0[4*k] = (f16)(v.x*inv); o0[4*k+1] = (f16)(v.y*inv);
    o0[4*k+2] = (f16)(v.z*inv); o0[4*k+3] = (f16)(v.w*inv);
    ap[k] = z;
  }
  #pragma unroll
  for (int k = 0; k < 2; k++){
    float4 v = ap[2+k];
    o1[4*k] = (f16)(v.x*inv); o1[4*k+1] = (f16)(v.y*inv);
    o1[4*k+2] = (f16)(v.z*inv); o1[4*k+3] = (f16)(v.w*inv);
    ap[2+k] = z;
  }
  *(f16x8*)&xh[(long)n * 16]     = o0;
  *(f16x8*)&xh[(long)n * 16 + 8] = o1;
}

// ============================================================================
// Fused EdgeConv1+EdgeConv2, BARRIER-FREE, 1 tile (64 edges) per block.
// NATURAL EDGE ORDER: act[e], ei[e], out[e] contiguous; only xh gathers random.
// ef folded into outAcc at conv1 time (linear functional).
// __launch_bounds__(256,5): spill-free (r8/r11/r12 verified: VGPR 48, WRITE 2.6MB).
// ============================================================================
__global__ __launch_bounds__(256, 5) void ec_mfma(
    const f16* __restrict__ xh1, const f16* __restrict__ xh2,
    const int* __restrict__ ei,
    const float* __restrict__ act, const f16* __restrict__ gf,
    const float* __restrict__ e1wc, const float* __restrict__ e1b0,
    const float* __restrict__ e1bh, const float* __restrict__ e1bc,
    const float* __restrict__ e2b0, const float* __restrict__ e2bh,
    const float* __restrict__ e2wc, const float* __restrict__ e2bc,
    float* __restrict__ outG, float* __restrict__ slacc)
{
  __shared__ __align__(16) f16 Hb[128 * 64];
  __shared__ float sred[4];

  const int t = threadIdx.x;
  const int lane = t & 63;
  const int wv = t >> 6;
  const int q = lane >> 4, n15 = lane & 15;
  const int eidx = (lane >> 1) & 15;      // edge within wave (staging)
  const int fh   = lane >> 5;             // 0: f1 rows, 1: f2 rows
  const int sub  = lane & 1;              // chunk pair selector
  const int myrow = fh * 64 + wv * 16 + eidx;
  const int gebase = blockIdx.x * 64;

  // staging node (f1=[x_d|x_s], f2=[x_s|x_d]); natural edge order, contiguous ei
  const int node = ei[((fh ^ sub) ? 0 : NEDGES) + gebase + wv * 16 + eidx];
  // this lane's output edge (contiguous act read / out write)
  const int e2 = gebase + wv * 16 + n15;
  const float aL = act[e2];

  const int rs = myrow & 7;
  auto write_lds = [&](f16x8 pa0, f16x8 pa1){
    f16* hp = &Hb[myrow << 6];
    *(f16x8*)&hp[((2*sub)     ^ rs) << 3] = pa0;
    *(f16x8*)&hp[((2*sub + 1) ^ rs) << 3] = pa1;
    if (sub){
      f16x8 z = {};
      *(f16x8*)&hp[(6 ^ rs) << 3] = z;
      *(f16x8*)&hp[(7 ^ rs) << 3] = z;
    }
  };

  float side = 0.f;
  float outAcc = 0.f;   // accumulates ef·wb at mode 2, then fe·wa at mode 3

  auto layer = [&](int lay, const float* bias, int nks, int mode){
    const int nEt = (mode == 2) ? 1 : 2;
    f32x4 C[3][2];
    #pragma unroll
    for (int wt = 0; wt < 3; wt++){
      float4 b4 = *(const float4*)&bias[wt*16 + 4*q];
      C[wt][0] = (f32x4){b4.x, b4.y, b4.z, b4.w};
      C[wt][1] = C[wt][0];
    }
    for (int ks = 0; ks < nks; ks++){
      int c = ks*4 + q;
      f16x8 Af[3];
      #pragma unroll
      for (int wt = 0; wt < 3; wt++)
        Af[wt] = *(const f16x8*)&gf[((((lay*2 + ks)*3) + wt) << 9) + (lane << 3)];
      for (int et = 0; et < nEt; et++){
        int r = (et << 6) + wv*16 + n15;
        f16x8 Bf = *(const f16x8*)&Hb[(r << 6) + ((c ^ (r & 7)) << 3)];
        #pragma unroll
        for (int wt = 0; wt < 3; wt++)
          C[wt][et] = __builtin_amdgcn_mfma_f32_16x16x32_f16(Af[wt], Bf, C[wt][et], 0, 0, 0);
      }
    }
    if (mode == 0){
      #pragma unroll
      for (int et = 0; et < 2; et++){
        int r = (et << 6) + wv*16 + n15;
        #pragma unroll
        for (int wt = 0; wt < 3; wt++){
          f16x4 pk;
          #pragma unroll
          for (int reg = 0; reg < 4; reg++) pk[reg] = (f16)fmaxf(C[wt][et][reg], 0.f);
          int col = wt*16 + 4*q;
          *(f16x4*)&Hb[(r << 6) + ((((col >> 3) ^ (r & 7)) << 3) | (col & 7))] = pk;
        }
      }
    } else if (mode == 1){
      int r = wv*16 + n15;
      #pragma unroll
      for (int wt = 0; wt < 3; wt++){
        f16x4 pk;
        #pragma unroll
        for (int reg = 0; reg < 4; reg++){
          float v1 = fmaxf(C[wt][0][reg], 0.f);
          float v2 = fmaxf(C[wt][1][reg], 0.f);
          float dd = v1 - v2; side += dd * dd;
          pk[reg] = (f16)(0.5f * (v1 + v2));
        }
        int col = wt*16 + 4*q;
        *(f16x4*)&Hb[(r << 6) + ((((col >> 3) ^ (r & 7)) << 3) | (col & 7))] = pk;
      }
    } else if (mode == 2){
      // ef = C + aL*wr; consumed only as sum(ef * e2wc[48..96]) -> fold now
      #pragma unroll
      for (int wt = 0; wt < 3; wt++){
        float4 wr = *(const float4*)&e1wc[2304 + wt*16 + 4*q];
        float4 wb = *(const float4*)&e2wc[48 + wt*16 + 4*q];
        outAcc += (C[wt][0][0] + aL * wr.x) * wb.x
                + (C[wt][0][1] + aL * wr.y) * wb.y
                + (C[wt][0][2] + aL * wr.z) * wb.z
                + (C[wt][0][3] + aL * wr.w) * wb.w;
      }
    } else {
      #pragma unroll
      for (int wt = 0; wt < 3; wt++){
        float4 wa = *(const float4*)&e2wc[wt*16 + 4*q];
        float av[4] = {wa.x, wa.y, wa.z, wa.w};
        #pragma unroll
        for (int reg = 0; reg < 4; reg++){
          float v1 = fmaxf(C[wt][0][reg], 0.f);
          float v2 = fmaxf(C[wt][1][reg], 0.f);
          float dd = v1 - v2; side += dd * dd;
          float fe = 0.5f * (v1 + v2);
          outAcc += fe * av[reg];
        }
      }
    }
  };

  // stage conv1 input (wave-private, no barrier)
  write_lds(*(const f16x8*)&xh1[(long)node * 16],
            *(const f16x8*)&xh1[(long)node * 16 + 8]);

  // ---- EdgeConv1 ----
  layer(0, e1b0,        1, 0);
  layer(1, e1bh + 0*48, 2, 0);
  layer(2, e1bh + 1*48, 2, 0);
  layer(3, e1bh + 2*48, 2, 0);

  // issue conv2 gather early: latency hides under layers 4-6
  f16x8 pf0 = *(const f16x8*)&xh2[(long)node * 16];
  f16x8 pf1 = *(const f16x8*)&xh2[(long)node * 16 + 8];

  layer(4, e1bh + 3*48, 2, 0);
  layer(5, e1bh + 4*48, 2, 1);
  layer(6, e1bc,        2, 2);   // ef·wb folded into outAcc (last Hb read of conv1)

  // restage same buffer from prefetched regs (wave-private, in-order DS)
  write_lds(pf0, pf1);

  // ---- EdgeConv2 ----
  layer(7,  e2b0,        1, 0);
  layer(8,  e2bh + 0*48, 2, 0);
  layer(9,  e2bh + 1*48, 2, 0);
  layer(10, e2bh + 2*48, 2, 0);
  layer(11, e2bh + 3*48, 2, 0);
  layer(12, e2bh + 4*48, 2, 3);  // fe·wa into outAcc

  {
    float v = outAcc;
    v += __shfl_xor(v, 16);
    v += __shfl_xor(v, 32);
    if (lane < 16) outG[e2] = v + e2bc[0];   // contiguous write
  }

  // side-loss: one atomic per block
  float sv = side;
  #pragma unroll
  for (int off = 32; off; off >>= 1) sv += __shfl_down(sv, off);
  if (lane == 0) sred[wv] = sv;
  __syncthreads();
  if (t == 0) atomicAdd(slacc, sred[0] + sred[1] + sred[2] + sred[3]);
}

// ================= launch ==================
extern "C" void kernel_launch(void* const* d_in, const int* in_sizes, int n_in,
                              void* d_out, int out_size, void* d_ws, size_t ws_size,
                              hipStream_t stream)
{
  if (n_in < 25) return;
  if (ws_size < (size_t)WS_NEED_FLOATS * sizeof(float)) return;

  const float* nf  = (const float*)d_in[0];
  const int*   ei  = (const int*)d_in[1];
  const float* ang = (const float*)d_in[2];
  const float* act = (const float*)d_in[4];
  const float* nc1_w0 = (const float*)d_in[5];
  const float* nc1_b0 = (const float*)d_in[6];
  const float* nc1_wh = (const float*)d_in[7];
  const float* nc1_bh = (const float*)d_in[8];
  const float* nc2_w0 = (const float*)d_in[9];
  const float* nc2_b0 = (const float*)d_in[10];
  const float* nc2_wh = (const float*)d_in[11];
  const float* nc2_bh = (const float*)d_in[12];
  const float* e1w0 = (const float*)d_in[13];
  const float* e1b0 = (const float*)d_in[14];
  const float* e1wh = (const float*)d_in[15];
  const float* e1bh = (const float*)d_in[16];
  const float* e1wc = (const float*)d_in[17];
  const float* e1bc = (const float*)d_in[18];
  const float* e2w0 = (const float*)d_in[19];
  const float* e2b0 = (const float*)d_in[20];
  const float* e2wh = (const float*)d_in[21];
  const float* e2bh = (const float*)d_in[22];
  const float* e2wc = (const float*)d_in[23];
  const float* e2bc = (const float*)d_in[24];

  float* ws  = (float*)d_ws;
  float* out = (float*)d_out;

  f16* xh1    = (f16*)(ws + OX1);
  f16* xh2    = (f16*)(ws + OX2);
  int* dstp   = (int*)(ws + ODSTP);
  float* agg  = ws + OAGG;
  int* rowptr = (int*)(ws + OROW);
  int* deg    = (int*)(ws + ODEG);
  f16* gf     = (f16*)(ws + OGF);
  f16* gfn    = gf + 39936;
  int* bsum   = (int*)(ws + OSCAN);
  int* boff   = bsum + 512;
  int* rank   = (int*)(ws + ORANK);
  int* perm   = (int*)(ws + OPERM);
  float* sl   = ws + OSL;

  const int eb  = (NEDGES + 255) / 256;
  const int nbN = (NNODES + 255) / 256;
  const int pfb = (39936 + 255) / 256;
  const int pnb = (12288 + 255) / 256;

  (void)hipMemsetAsync(deg, 0, (size_t)NNODES * sizeof(int), stream);
  (void)hipMemsetAsync(sl, 0, sizeof(float), stream);

  hipLaunchKernelGGL(count_deg, dim3(eb), dim3(256), 0, stream, ei, deg, rank);
  hipLaunchKernelGGL(scan_p1, dim3(NBS), dim3(256), 0, stream, deg, bsum);
  hipLaunchKernelGGL(scan_p2, dim3(1), dim3(512), 0, stream, bsum, boff, rowptr);
  hipLaunchKernelGGL(scan_p3, dim3(NBS), dim3(256), 0, stream, deg, boff, rowptr);
  // atomic-free scatter; also materializes position-indexed dstp
  hipLaunchKernelGGL(scatter_perm, dim3(eb), dim3(256), 0, stream, ei, rowptr, rank, perm, dstp);

  hipLaunchKernelGGL(prep_wfrag, dim3(pfb), dim3(256), 0, stream,
      e1w0, e1wh, e1wc, e2w0, e2wh, gf);
  hipLaunchKernelGGL(prep_wfrag_nc, dim3(pnb), dim3(256), 0, stream,
      nc1_w0, nc1_wh, nc2_w0, nc2_wh, gfn);

  // NodeConv1: fp32 nf -> agg -> xh1 (node_finh re-zeroes agg for NC2)
  // (agg memset also retires the scan/rank scratch aliased at OAGG)
  (void)hipMemsetAsync(agg, 0, (size_t)NNODES * 16 * sizeof(float), stream);
  hipLaunchKernelGGL((nc_mfma<true>), dim3(eb), dim3(256), 0, stream,
      (const void*)nf, ei, ang, perm, dstp, gfn, nc1_w0, nc1_b0, nc1_bh, agg);
  hipLaunchKernelGGL(node_finh, dim3(nbN), dim3(256), 0, stream, agg, rowptr, xh1);

  // NodeConv2: f16 xh1 -> agg -> xh2 (dstp still live; xh2 written after nc2)
  hipLaunchKernelGGL((nc_mfma<false>), dim3(eb), dim3(256), 0, stream,
      (const void*)xh1, ei, ang, perm, dstp, gfn + 12 * 512, nc2_w0, nc2_b0, nc2_bh, agg);
  hipLaunchKernelGGL(node_finh, dim3(nbN), dim3(256), 0, stream, agg, rowptr, xh2);

  // fused EdgeConv1+2: natural edge order, all IO contiguous except xh gathers
  hipLaunchKernelGGL(ec_mfma, dim3(ECNB), dim3(256), 0, stream,
      xh1, xh2, ei, act, gf,
      e1wc, e1b0, e1bh, e1bc, e2b0, e2bh, e2wc, e2bc,
      out, sl);

  hipLaunchKernelGGL(fin_loss, dim3(1), dim3(1), 0, stream, sl, out);
}